// Round 16
// baseline (926.870 us; speedup 1.0000x reference)
//
#include <hip/hip_runtime.h>
#include <stdint.h>

typedef unsigned short u16;
typedef unsigned int   u32;

#define D_MODEL 1024
#define NHEADS  16
#define DKH     64
#define DFF     4096
#define NLAYERS 4
#define BATCH   2
#define SEQ     1024
#define NTOK    (BATCH*SEQ)
#define NVOCAB  32000
#define QKV_LD  3072

typedef __bf16 bf16x8 __attribute__((ext_vector_type(8)));
typedef float  f32x4  __attribute__((ext_vector_type(4)));
typedef u32    u32x4  __attribute__((ext_vector_type(4)));

static __device__ __forceinline__ u16 f2bf(float f){
    union { float f; u32 u; } v; v.f = f;
    return (u16)((v.u + 0x7fffu + ((v.u >> 16) & 1u)) >> 16);
}
static __device__ __forceinline__ u32 pk2(float lo, float hi){
    return (u32)f2bf(lo) | ((u32)f2bf(hi) << 16);
}
static __device__ __forceinline__ bf16x8 ldb8(const u16* p){
    return *reinterpret_cast<const bf16x8*>(p);
}
static __device__ __forceinline__ f32x4 mfma16(bf16x8 a, bf16x8 b, f32x4 c){
    return __builtin_amdgcn_mfma_f32_16x16x32_bf16(a, b, c, 0, 0, 0);
}
static __device__ __forceinline__ void gld16(const void* g, void* l){
    __builtin_amdgcn_global_load_lds((__attribute__((address_space(1))) u32*)g,
                                     (__attribute__((address_space(3))) u32*)l, 16, 0, 0);
}

// ---------------- embedding: x = tok[id]*sqrt(d) + pe[s] ----------------
__global__ __launch_bounds__(256) void k_embed(const int* __restrict__ ids,
        const float* __restrict__ tok, const float* __restrict__ pe,
        float* __restrict__ x){
    int t = blockIdx.x;
    int c = threadIdx.x * 4;
    int id = ids[t];
    int s = t & (SEQ - 1);
    float4 tv = *(const float4*)(tok + (size_t)id * D_MODEL + c);
    float4 pv = *(const float4*)(pe  + (size_t)s  * D_MODEL + c);
    float4 o;
    o.x = tv.x * 32.0f + pv.x;
    o.y = tv.y * 32.0f + pv.y;
    o.z = tv.z * 32.0f + pv.z;
    o.w = tv.w * 32.0f + pv.w;
    *(float4*)(x + (size_t)t * D_MODEL + c) = o;
}

// ---------------- layernorm (f32 in -> bf16 out) ----------------
__global__ __launch_bounds__(256) void k_ln(const float* __restrict__ x,
        const float* __restrict__ g, const float* __restrict__ b,
        u16* __restrict__ out){
    int t = blockIdx.x;
    int tid = threadIdx.x;
    float4 v = *(const float4*)(x + (size_t)t * D_MODEL + tid * 4);
    float s  = v.x + v.y + v.z + v.w;
    float ss = v.x*v.x + v.y*v.y + v.z*v.z + v.w*v.w;
    #pragma unroll
    for (int off = 1; off < 64; off <<= 1){
        s  += __shfl_xor(s, off);
        ss += __shfl_xor(ss, off);
    }
    __shared__ float rs[4], rss[4];
    int w = tid >> 6;
    if ((tid & 63) == 0){ rs[w] = s; rss[w] = ss; }
    __syncthreads();
    s  = rs[0] + rs[1] + rs[2] + rs[3];
    ss = rss[0] + rss[1] + rss[2] + rss[3];
    float mu  = s * (1.0f / D_MODEL);
    float var = ss * (1.0f / D_MODEL) - mu * mu;
    float rstd = rsqrtf(var + 1e-5f);
    float4 gg = *(const float4*)(g + tid * 4);
    float4 bb = *(const float4*)(b + tid * 4);
    uint2 pkv;
    pkv.x = pk2((v.x - mu) * rstd * gg.x + bb.x, (v.y - mu) * rstd * gg.y + bb.y);
    pkv.y = pk2((v.z - mu) * rstd * gg.z + bb.z, (v.w - mu) * rstd * gg.w + bb.w);
    *(uint2*)(out + (size_t)t * D_MODEL + tid * 4) = pkv;
}

// ------- layernorm with fused split-K combine: xn = x + sum(p) + bias -------
template<int NP>
__global__ __launch_bounds__(256) void k_ln_acc(float* __restrict__ x,
        const float* __restrict__ pb,
        const float* __restrict__ bias,
        const float* __restrict__ g, const float* __restrict__ b,
        u16* __restrict__ out){
    int t = blockIdx.x;
    int tid = threadIdx.x;
    size_t idx = (size_t)t * D_MODEL + tid * 4;
    float4 v  = *(const float4*)(x + idx);
    float4 bv = *(const float4*)(bias + tid * 4);
    v.x += bv.x; v.y += bv.y; v.z += bv.z; v.w += bv.w;
    #pragma unroll
    for (int p = 0; p < NP; p++){
        float4 a = *(const float4*)(pb + (size_t)p * NTOK * D_MODEL + idx);
        v.x += a.x; v.y += a.y; v.z += a.z; v.w += a.w;
    }
    *(float4*)(x + idx) = v;
    float s  = v.x + v.y + v.z + v.w;
    float ss = v.x*v.x + v.y*v.y + v.z*v.z + v.w*v.w;
    #pragma unroll
    for (int off = 1; off < 64; off <<= 1){
        s  += __shfl_xor(s, off);
        ss += __shfl_xor(ss, off);
    }
    __shared__ float rs[4], rss[4];
    int w = tid >> 6;
    if ((tid & 63) == 0){ rs[w] = s; rss[w] = ss; }
    __syncthreads();
    s  = rs[0] + rs[1] + rs[2] + rs[3];
    ss = rss[0] + rss[1] + rss[2] + rss[3];
    float mu  = s * (1.0f / D_MODEL);
    float var = ss * (1.0f / D_MODEL) - mu * mu;
    float rstd = rsqrtf(var + 1e-5f);
    float4 gg = *(const float4*)(g + tid * 4);
    float4 bb = *(const float4*)(b + tid * 4);
    uint2 pkv;
    pkv.x = pk2((v.x - mu) * rstd * gg.x + bb.x, (v.y - mu) * rstd * gg.y + bb.y);
    pkv.y = pk2((v.z - mu) * rstd * gg.z + bb.z, (v.w - mu) * rstd * gg.w + bb.w);
    *(uint2*)(out + idx) = pkv;
}

// ------------- Whead f32 -> bf16 cast (same layout [N,K]) -------------
__global__ __launch_bounds__(256) void k_cast(const float* __restrict__ in,
        u16* __restrict__ out){
    size_t i = ((size_t)blockIdx.x * 256 + threadIdx.x) * 8;
    float4 a = *(const float4*)(in + i);
    float4 b = *(const float4*)(in + i + 4);
    u32x4 o;
    o.x = pk2(a.x, a.y); o.y = pk2(a.z, a.w);
    o.z = pk2(b.x, b.y); o.w = pk2(b.z, b.w);
    *(u32x4*)(out + i) = o;
}

// ------------- fused per-layer weight transpose+convert -------------
__global__ __launch_bounds__(256) void k_tconv_fused(
        const float* __restrict__ Wq, const float* __restrict__ Wk,
        const float* __restrict__ Wv, const float* __restrict__ Wo,
        const float* __restrict__ W1, const float* __restrict__ W2,
        u16* __restrict__ wqkvT, u16* __restrict__ woT,
        u16* __restrict__ w1T,   u16* __restrict__ w2T){
    __shared__ float tile[32][33];
    const int id = blockIdx.x;
    const float* in; u16* outp; int R, C, bx, by;
    if (id < 4096){
        int wsel = id >> 10, t = id & 1023;
        bx = t & 31; by = t >> 5; R = 1024; C = 1024;
        in   = (wsel == 0) ? Wq : (wsel == 1) ? Wk : (wsel == 2) ? Wv : Wo;
        outp = (wsel < 3) ? wqkvT + wsel * 1024 * 1024 : woT;
    } else if (id < 8192){
        int t = id - 4096; bx = t & 127; by = t >> 7;
        R = 1024; C = 4096; in = W1; outp = w1T;
    } else {
        int t = id - 8192; bx = t & 31; by = t >> 5;
        R = 4096; C = 1024; in = W2; outp = w2T;
    }
    const int tx = threadIdx.x & 31, ty = threadIdx.x >> 5;
    #pragma unroll
    for (int i = 0; i < 4; i++){
        int r = by * 32 + ty + i * 8;
        tile[ty + i * 8][tx] = in[(size_t)r * C + bx * 32 + tx];
    }
    __syncthreads();
    #pragma unroll
    for (int i = 0; i < 4; i++){
        int c = bx * 32 + ty + i * 8;
        outp[(size_t)c * R + by * 32 + tx] = f2bf(tile[tx][ty + i * 8]);
    }
}

// ------------- V (inside qkv) -> Vt[b,h,dh,s] bf16 -------------
__global__ __launch_bounds__(256) void k_vt(const u16* __restrict__ qkv,
        u16* __restrict__ vt){
    __shared__ u16 tile[32][33];
    int sb = blockIdx.x;
    int yz = blockIdx.y;
    int db = yz & 1;
    int bh = yz >> 1;
    int b = bh >> 4, h = bh & 15;
    int tx = threadIdx.x & 31, ty = threadIdx.x >> 5;
    #pragma unroll
    for (int i = 0; i < 4; i++){
        int s = sb * 32 + ty + i * 8;
        tile[ty + i * 8][tx] = qkv[(size_t)(b * SEQ + s) * QKV_LD + 2048 + h * DKH + db * 32 + tx];
    }
    __syncthreads();
    #pragma unroll
    for (int i = 0; i < 4; i++){
        int dh = db * 32 + ty + i * 8;
        vt[(size_t)(bh * DKH + dh) * SEQ + sb * 32 + tx] = tile[tx][ty + i * 8];
    }
}

// ---------------- 128-tile deep-pipelined GEMM (layer GEMMs) ----------------
// counted vmcnt(8), raw barriers, both-sides XOR swizzle, setprio.
// 128x128 tile / 4 waves / BK=64, 64 KiB LDS -> 2 blocks/CU.
template<bool BIAS, bool RELU, bool OBF16, bool AXISM>
__global__ __launch_bounds__(256, 2) void k_gemm128p(
    const u16* __restrict__ A, const u16* __restrict__ Bt,
    const float* __restrict__ bias,
    float* __restrict__ outF, u16* __restrict__ outH,
    int N, int Kfull, int NXT, int NMT, int NZ)
{
    __shared__ __align__(16) u16 lds[32768];  // 2 slots x (A 8K + B 8K) elems
    const int bid = blockIdx.x;
    const int xcd = bid & 7;
    const int r   = bid >> 3;
    int m_t, n_t, z;
    if constexpr (AXISM) {
        const int mper = NMT >> 3;
        n_t = r % NXT;
        int r2 = r / NXT;
        z = r2 % NZ;
        m_t = xcd * mper + r2 / NZ;
    } else {
        const int nper = NXT >> 3;
        n_t = xcd * nper + r % nper;
        int r2 = r / nper;
        m_t = r2 % NMT;
        z = r2 / NMT;
    }
    const int m0 = m_t * 128;
    const int n0 = n_t * 128;
    const int Kz = Kfull / NZ;
    const int kbeg = z * Kz;
    const int NT = Kz >> 6;

    const int tid  = threadIdx.x;
    const int w    = tid >> 6;
    const int lane = tid & 63;
    const int wr   = w >> 1, wc = w & 1;            // 2m x 2n wave grid
    const int lrow = lane & 15, lkg = lane >> 4;

    // --- staging addressing ---
    const int srow = tid >> 3;                       // 0..31 row within chunk
    const int ssw  = ((tid & 7) ^ (srow & 7)) * 8;   // pre-swizzled 16B slot
    const u16* aSrc0 = A  + (size_t)(m0 +  0 + srow) * Kfull + kbeg + ssw;
    const u16* aSrc1 = A  + (size_t)(m0 + 32 + srow) * Kfull + kbeg + ssw;
    const u16* aSrc2 = A  + (size_t)(m0 + 64 + srow) * Kfull + kbeg + ssw;
    const u16* aSrc3 = A  + (size_t)(m0 + 96 + srow) * Kfull + kbeg + ssw;
    const u16* bSrc0 = Bt + (size_t)(n0 +  0 + srow) * Kfull + kbeg + ssw;
    const u16* bSrc1 = Bt + (size_t)(n0 + 32 + srow) * Kfull + kbeg + ssw;
    const u16* bSrc2 = Bt + (size_t)(n0 + 64 + srow) * Kfull + kbeg + ssw;
    const u16* bSrc3 = Bt + (size_t)(n0 + 96 + srow) * Kfull + kbeg + ssw;

    // --- frag-read addressing ---
    const int sw0 = ((0 + lkg) ^ (lrow & 7)) * 8;
    const int sw1 = ((4 + lkg) ^ (lrow & 7)) * 8;
    const int aBase = (wr * 64 + lrow) * 64;
    const int bBase = (wc * 64 + lrow) * 64 + 8192;

    f32x4 acc[4][4] = {};

    #define STAGE(s, st) do { \
        u16* ab_ = lds + (s) * 16384 + w * 512; \
        const int ko_ = (st) * 64; \
        gld16(aSrc0 + ko_, ab_);              \
        gld16(aSrc1 + ko_, ab_ + 2048);       \
        gld16(aSrc2 + ko_, ab_ + 4096);       \
        gld16(aSrc3 + ko_, ab_ + 6144);       \
        gld16(bSrc0 + ko_, ab_ + 8192);       \
        gld16(bSrc1 + ko_, ab_ + 10240);      \
        gld16(bSrc2 + ko_, ab_ + 12288);      \
        gld16(bSrc3 + ko_, ab_ + 14336);      \
    } while (0)

    STAGE(0, 0);
    STAGE(1, 1);
    asm volatile("s_waitcnt vmcnt(8)" ::: "memory");
    __builtin_amdgcn_s_barrier();
    __builtin_amdgcn_sched_barrier(0);

    for (int t = 0; t < NT; ++t){
        const int s = t & 1;
        const u16* As = lds + s * 16384;

        bf16x8 af0[4], bf0[4];
        #pragma unroll
        for (int i = 0; i < 4; i++) af0[i] = ldb8(As + aBase + i * 1024 + sw0);
        #pragma unroll
        for (int j = 0; j < 4; j++) bf0[j] = ldb8(As + bBase + j * 1024 + sw0);
        __builtin_amdgcn_s_setprio(1);
        #pragma unroll
        for (int i = 0; i < 4; i++)
            #pragma unroll
            for (int j = 0; j < 4; j++)
                acc[i][j] = mfma16(af0[i], bf0[j], acc[i][j]);
        __builtin_amdgcn_s_setprio(0);

        bf16x8 af1[4], bf1[4];
        #pragma unroll
        for (int i = 0; i < 4; i++) af1[i] = ldb8(As + aBase + i * 1024 + sw1);
        #pragma unroll
        for (int j = 0; j < 4; j++) bf1[j] = ldb8(As + bBase + j * 1024 + sw1);
        asm volatile("s_waitcnt lgkmcnt(0)" ::: "memory");
        __builtin_amdgcn_sched_barrier(0);
        __builtin_amdgcn_s_barrier();          // all waves done reading slot s
        __builtin_amdgcn_sched_barrier(0);

        STAGE(s, (t + 2 < NT) ? t + 2 : NT - 1);

        __builtin_amdgcn_s_setprio(1);
        #pragma unroll
        for (int i = 0; i < 4; i++)
            #pragma unroll
            for (int j = 0; j < 4; j++)
                acc[i][j] = mfma16(af1[i], bf1[j], acc[i][j]);
        __builtin_amdgcn_s_setprio(0);

        asm volatile("s_waitcnt vmcnt(8)" ::: "memory");
        __builtin_amdgcn_s_barrier();          // slot s^1 (t+1) now ready
        __builtin_amdgcn_sched_barrier(0);
    }
    #undef STAGE

    float* outFz = outF;
    if (NZ > 1) outFz += (size_t)z * (NMT * 128) * N;

    #pragma unroll
    for (int i = 0; i < 4; i++){
        #pragma unroll
        for (int j = 0; j < 4; j++){
            const int c = n0 + 64 * wc + 16 * j + lrow;
            float bv = 0.0f;
            if constexpr (BIAS) bv = bias[c];
            #pragma unroll
            for (int e = 0; e < 4; e++){
                const int rr = m0 + 64 * wr + 16 * i + lkg * 4 + e;
                float vv = acc[i][j][e] + bv;
                if constexpr (RELU) vv = fmaxf(vv, 0.0f);
                const size_t idx = (size_t)rr * N + c;
                if constexpr (OBF16) outH[idx] = f2bf(vv);
                else                 outFz[idx] = vv;
            }
        }
    }
}

// ---------------- head GEMM: 256x256 tile, 512 thr, BK=64, deep pipeline ----
// (validated: 176-182 us, FETCH 115 MB, bank-conflict 0 — best measured head)
__global__ __launch_bounds__(512, 2) void k_gemm_head256(
    const u16* __restrict__ A, const u16* __restrict__ Bt,
    float* __restrict__ out)
{
    __shared__ __align__(16) u16 lds[65536];
    const int bid = blockIdx.x;
    const int swz = (bid & 7) * 125 + (bid >> 3);   // XCD-chunked, 1000%8==0
    const int m0 = (swz >> 3) * 256;                // vocab tile
    const int n0 = (swz & 7) * 256;                 // token tile

    const int tid  = threadIdx.x;
    const int w    = tid >> 6;
    const int lane = tid & 63;
    const int wr   = w >> 2, wc = w & 3;            // 2m x 4n wave grid
    const int lrow = lane & 15, lkg = lane >> 4;

    const int srow = tid >> 3;
    const int ssw  = ((tid & 7) ^ (srow & 7)) * 8;
    const u16* aSrc0 = A  + (size_t)(m0 +   0 + srow) * D_MODEL + ssw;
    const u16* aSrc1 = A  + (size_t)(m0 +  64 + srow) * D_MODEL + ssw;
    const u16* aSrc2 = A  + (size_t)(m0 + 128 + srow) * D_MODEL + ssw;
    const u16* aSrc3 = A  + (size_t)(m0 + 192 + srow) * D_MODEL + ssw;
    const u16* bSrc0 = Bt + (size_t)(n0 +   0 + srow) * D_MODEL + ssw;
    const u16* bSrc1 = Bt + (size_t)(n0 +  64 + srow) * D_MODEL + ssw;
    const u16* bSrc2 = Bt + (size_t)(n0 + 128 + srow) * D_MODEL + ssw;
    const u16* bSrc3 = Bt + (size_t)(n0 + 192 + srow) * D_MODEL + ssw;

    const int sw0 = ((0 + lkg) ^ (lrow & 7)) * 8;
    const int sw1 = ((4 + lkg) ^ (lrow & 7)) * 8;
    const int aBase = (wr * 128 + lrow) * 64;
    const int bBase = (wc * 64  + lrow) * 64;

    f32x4 acc[8][4] = {};

    #define STAGE(s, st) do { \
        u16* ab_ = lds + (s) * 32768 + w * 512; \
        const int ko_ = (st) * 64; \
        gld16(aSrc0 + ko_, ab_);              \
        gld16(aSrc1 + ko_, ab_ + 4096);       \
        gld16(aSrc2 + ko_, ab_ + 8192);       \
        gld16(aSrc3 + ko_, ab_ + 12288);      \
        gld16(bSrc0 + ko_, ab_ + 16384);      \
        gld16(bSrc1 + ko_, ab_ + 20480);      \
        gld16(bSrc2 + ko_, ab_ + 24576);      \
        gld16(bSrc3 + ko_, ab_ + 28672);      \
    } while (0)

    STAGE(0, 0);
    STAGE(1, 1);
    asm volatile("s_waitcnt vmcnt(8)" ::: "memory");
    __builtin_amdgcn_s_barrier();
    __builtin_amdgcn_sched_barrier(0);

    const int NT = D_MODEL / 64;   // 16
    for (int t = 0; t < NT; ++t){
        const int s = t & 1;
        const u16* As = lds + s * 32768;
        const u16* Bs = As + 16384;

        bf16x8 af0[8], bf0[4];
        #pragma unroll
        for (int i = 0; i < 8; i++) af0[i] = ldb8(As + aBase + i * 1024 + sw0);
        #pragma unroll
        for (int j = 0; j < 4; j++) bf0[j] = ldb8(Bs + bBase + j * 1024 + sw0);
        __builtin_amdgcn_s_setprio(1);
        #pragma unroll
        for (int i = 0; i < 8; i++)
            #pragma unroll
            for (int j = 0; j < 4; j++)
                acc[i][j] = mfma16(af0[i], bf0[j], acc[i][j]);
        __builtin_amdgcn_s_setprio(0);

        bf16x8 af1[8], bf1[4];
        #pragma unroll
        for (int i = 0; i < 8; i++) af1[i] = ldb8(As + aBase + i * 1024 + sw1);
        #pragma unroll
        for (int j = 0; j < 4; j++) bf1[j] = ldb8(Bs + bBase + j * 1024 + sw1);
        asm volatile("s_waitcnt lgkmcnt(0)" ::: "memory");
        __builtin_amdgcn_sched_barrier(0);
        __builtin_amdgcn_s_barrier();
        __builtin_amdgcn_sched_barrier(0);

        STAGE(s, (t + 2 < NT) ? t + 2 : NT - 1);

        __builtin_amdgcn_s_setprio(1);
        #pragma unroll
        for (int i = 0; i < 8; i++)
            #pragma unroll
            for (int j = 0; j < 4; j++)
                acc[i][j] = mfma16(af1[i], bf1[j], acc[i][j]);
        __builtin_amdgcn_s_setprio(0);

        asm volatile("s_waitcnt vmcnt(8)" ::: "memory");
        __builtin_amdgcn_s_barrier();
        __builtin_amdgcn_sched_barrier(0);
    }
    #undef STAGE

    #pragma unroll
    for (int i = 0; i < 8; i++){
        const int m = m0 + wr * 128 + i * 16 + lkg * 4;
        #pragma unroll
        for (int j = 0; j < 4; j++){
            const int n = n0 + wc * 64 + j * 16 + lrow;
            float4 st;
            st.x = acc[i][j][0]; st.y = acc[i][j][1];
            st.z = acc[i][j][2]; st.w = acc[i][j][3];
            *(float4*)(out + (size_t)n * NVOCAB + m) = st;
        }
    }
}

// ---------------- flash attention: 1 wave per 16-row q-tile, KVBLK=64 -------
__global__ __launch_bounds__(256) void k_attn(const u16* __restrict__ qkv,
        const u16* __restrict__ vt, u16* __restrict__ ctx){
    const int wid  = (blockIdx.x << 2) + (threadIdx.x >> 6);
    const int lane = threadIdx.x & 63;
    const int qt = wid & 63;
    const int h  = (wid >> 6) & 15;
    const int b  = wid >> 10;
    const int q0 = qt * 16;
    const int lrow = lane & 15, lkg = lane >> 4;

    __shared__ __align__(16) u16 plds_all[4][16][72]; // 144B rows, 16B-aligned
    u16 (*plds)[72] = plds_all[threadIdx.x >> 6];

    const u16* qbase = qkv + (size_t)(b * SEQ + q0 + lrow) * QKV_LD + h * DKH + 8 * lkg;
    const bf16x8 qf0 = ldb8(qbase);
    const bf16x8 qf1 = ldb8(qbase + 32);

    float mr[4], lsum[4];
    f32x4 acc[4] = {};
    #pragma unroll
    for (int e = 0; e < 4; e++){ mr[e] = -1e30f; lsum[e] = 0.0f; }

    const int nkb = (q0 >> 6) + 1;
    const u16* kbase  = qkv + (size_t)(b * SEQ) * QKV_LD + 1024 + h * DKH;
    const u16* vtbase = vt + (size_t)((b * NHEADS + h) * DKH) * SEQ;

    for (int kb = 0; kb < nkb; ++kb){
        const int kc = kb * 64;
        f32x4 sg[4] = {};
        const u16* kp = kbase + (size_t)(kc + lrow) * QKV_LD + 8 * lkg;
        bf16x8 ka[4], kbv[4];
        #pragma unroll
        for (int g = 0; g < 4; g++){
            const u16* p = kp + (size_t)(16 * g) * QKV_LD;
            ka[g]  = ldb8(p);
            kbv[g] = ldb8(p + 32);
        }
        __builtin_amdgcn_s_setprio(1);
        #pragma unroll
        for (int g = 0; g < 4; g++){
            sg[g] = mfma16(qf0, ka[g],  sg[g]);
            sg[g] = mfma16(qf1, kbv[g], sg[g]);
        }
        __builtin_amdgcn_s_setprio(0);

        #pragma unroll
        for (int e = 0; e < 4; e++){
            const int row = q0 + lkg * 4 + e;
            float v0 = (kc      + lrow > row) ? -1e30f : sg[0][e] * 0.125f;
            float v1 = (kc + 16 + lrow > row) ? -1e30f : sg[1][e] * 0.125f;
            float v2 = (kc + 32 + lrow > row) ? -1e30f : sg[2][e] * 0.125f;
            float v3 = (kc + 48 + lrow > row) ? -1e30f : sg[3][e] * 0.125f;
            float t = fmaxf(fmaxf(v0, v1), fmaxf(v2, v3));
            t = fmaxf(t, __shfl_xor(t, 1));
            t = fmaxf(t, __shfl_xor(t, 2));
            t = fmaxf(t, __shfl_xor(t, 4));
            t = fmaxf(t, __shfl_xor(t, 8));
            const float mn = fmaxf(mr[e], t);
            const float al = __expf(mr[e] - mn);
            const float p0 = __expf(v0 - mn);
            const float p1 = __expf(v1 - mn);
            const float p2 = __expf(v2 - mn);
            const float p3 = __expf(v3 - mn);
            float rsum = (p0 + p1) + (p2 + p3);
            rsum += __shfl_xor(rsum, 1);
            rsum += __shfl_xor(rsum, 2);
            rsum += __shfl_xor(rsum, 4);
            rsum += __shfl_xor(rsum, 8);
            lsum[e] = lsum[e] * al + rsum;
            mr[e] = mn;
            #pragma unroll
            for (int nt = 0; nt < 4; nt++) acc[nt][e] *= al;
            u16* prow = plds[lkg * 4 + e];
            prow[lrow]      = f2bf(p0);
            prow[16 + lrow] = f2bf(p1);
            prow[32 + lrow] = f2bf(p2);
            prow[48 + lrow] = f2bf(p3);
        }
        asm volatile("" ::: "memory"); // keep P writes before the frag read
        const bf16x8 pf0 = ldb8(&plds[lrow][8 * lkg]);
        const bf16x8 pf1 = ldb8(&plds[lrow][32 + 8 * lkg]);
        __builtin_amdgcn_s_setprio(1);
        #pragma unroll
        for (int nt = 0; nt < 4; nt++){
            const u16* vp = vtbase + (size_t)(16 * nt + lrow) * SEQ + kc + 8 * lkg;
            acc[nt] = mfma16(pf0, ldb8(vp),      acc[nt]);
            acc[nt] = mfma16(pf1, ldb8(vp + 32), acc[nt]);
        }
        __builtin_amdgcn_s_setprio(0);
    }
    #pragma unroll
    for (int nt = 0; nt < 4; nt++){
        #pragma unroll
        for (int e = 0; e < 4; e++){
            const int r = q0 + lkg * 4 + e;
            ctx[(size_t)(b * SEQ + r) * D_MODEL + h * DKH + 16 * nt + lrow] =
                f2bf(acc[nt][e] / lsum[e]);
        }
    }
}

// ---------------- launcher ----------------
extern "C" void kernel_launch(void* const* d_in, const int* in_sizes, int n_in,
                              void* d_out, int out_size, void* d_ws, size_t ws_size,
                              hipStream_t stream){
    const int*   ids  = (const int*)  d_in[0];
    const float* tok  = (const float*)d_in[1];
    const float* pe   = (const float*)d_in[2];
    const float* Wq   = (const float*)d_in[3];
    const float* Wk   = (const float*)d_in[4];
    const float* Wv   = (const float*)d_in[5];
    const float* Wo   = (const float*)d_in[6];
    const float* bo   = (const float*)d_in[7];
    const float* W1   = (const float*)d_in[8];
    const float* b1   = (const float*)d_in[9];
    const float* W2   = (const float*)d_in[10];
    const float* b2   = (const float*)d_in[11];
    const float* ln1g = (const float*)d_in[12];
    const float* ln1b = (const float*)d_in[13];
    const float* ln2g = (const float*)d_in[14];
    const float* ln2b = (const float*)d_in[15];
    const float* lnfg = (const float*)d_in[16];
    const float* lnfb = (const float*)d_in[17];
    const float* Wh   = (const float*)d_in[18];
    float* out = (float*)d_out;

    char* ws = (char*)d_ws;
    size_t off = 0;
    auto alloc = [&](size_t bytes) -> void* {
        void* p = ws + off;
        off += (bytes + 255) & ~(size_t)255;
        return p;
    };
    float* x     = (float*)alloc((size_t)NTOK * D_MODEL * 4);   // 8 MB
    u16*   hbuf  = (u16*)  alloc((size_t)NTOK * D_MODEL * 2);   // 4 MB
    u16*   qkv   = (u16*)  alloc((size_t)NTOK * QKV_LD  * 2);   // 12 MB
    u16*   vt    = (u16*)  alloc((size_t)NTOK * D_MODEL * 2);   // 4 MB
    u16*   ctx   = (u16*)  alloc((size_t)NTOK * D_MODEL * 2);   // 4 MB
    u16*   f1    = (u16*)  alloc((size_t)NTOK * DFF     * 2);   // 16 MB
    float* pbuf  = (float*)alloc((size_t)4 * NTOK * D_MODEL * 4); // 32 MB (4 split-K partials)
    u16*   wqkvT = (u16*)  alloc((size_t)QKV_LD * D_MODEL * 2); // 6 MB
    u16*   woT   = (u16*)  alloc((size_t)D_MODEL * D_MODEL * 2);// 2 MB
    u16*   w1T   = (u16*)  alloc((size_t)DFF * D_MODEL * 2);    // 8 MB
    u16*   w2T   = (u16*)  alloc((size_t)D_MODEL * DFF * 2);    // 8 MB
    u16*   whB   = (u16*)  alloc((size_t)NVOCAB * D_MODEL * 2); // 65.5 MB
    (void)ws_size; (void)in_sizes; (void)n_in; (void)out_size;

    k_embed<<<NTOK, 256, 0, stream>>>(ids, tok, pe, x);
    k_cast<<<(NVOCAB * D_MODEL) / (256 * 8), 256, 0, stream>>>(Wh, whB);

    for (int l = 0; l < NLAYERS; l++){
        const size_t wdd = (size_t)l * D_MODEL * D_MODEL;
        const size_t wdf = (size_t)l * D_MODEL * DFF;
        k_tconv_fused<<<12288, 256, 0, stream>>>(
            Wq + wdd, Wk + wdd, Wv + wdd, Wo + wdd, W1 + wdf, W2 + wdf,
            wqkvT, woT, w1T, w2T);

        if (l == 0)
            k_ln<<<NTOK, 256, 0, stream>>>(x, ln1g, ln1b, hbuf);
        else
            k_ln_acc<4><<<NTOK, 256, 0, stream>>>(x, pbuf, b2 + (l - 1) * D_MODEL,
                ln1g + l * D_MODEL, ln1b + l * D_MODEL, hbuf);

        // QKV GEMM: grid 384 = 8 xcd * 3 n * 16 m (plain epilogue; k_vt restored)
        k_gemm128p<false, false, true, false><<<384, 256, 0, stream>>>(
            hbuf, wqkvT, nullptr, nullptr, qkv, QKV_LD, D_MODEL, 24, 16, 1);
        k_vt<<<dim3(32, 64), 256, 0, stream>>>(qkv, vt);
        k_attn<<<512, 256, 0, stream>>>(qkv, vt, ctx);

        // Wo GEMM split-K=2: grid 256
        k_gemm128p<false, false, false, true><<<256, 256, 0, stream>>>(
            ctx, woT, nullptr, pbuf, nullptr, D_MODEL, D_MODEL, 8, 16, 2);
        k_ln_acc<2><<<NTOK, 256, 0, stream>>>(x, pbuf, bo + l * D_MODEL,
            ln2g + l * D_MODEL, ln2b + l * D_MODEL, hbuf);

        // W1 GEMM: grid 512 = 8 xcd * 4 n * 16 m
        k_gemm128p<true, true, true, false><<<512, 256, 0, stream>>>(
            hbuf, w1T, b1 + l * DFF, nullptr, f1, DFF, D_MODEL, 32, 16, 1);
        // W2 GEMM split-K=4: grid 512 -> 2 blocks/CU (kept from r15 for A/B)
        k_gemm128p<false, false, false, true><<<512, 256, 0, stream>>>(
            f1, w2T, nullptr, pbuf, nullptr, D_MODEL, DFF, 8, 16, 4);
    }

    k_ln_acc<4><<<NTOK, 256, 0, stream>>>(x, pbuf, b2 + 3 * D_MODEL,
        lnfg, lnfb, hbuf);
    // head GEMM: k_gemm_head256 — best measured (176-182 us, FETCH 115MB).
    k_gemm_head256<<<1000, 512, 0, stream>>>(whB, hbuf, out);
}

// Round 17
// 911.960 us; speedup vs baseline: 1.0163x; 1.0163x over previous
//
#include <hip/hip_runtime.h>
#include <stdint.h>

typedef unsigned short u16;
typedef unsigned int   u32;

#define D_MODEL 1024
#define NHEADS  16
#define DKH     64
#define DFF     4096
#define NLAYERS 4
#define BATCH   2
#define SEQ     1024
#define NTOK    (BATCH*SEQ)
#define NVOCAB  32000
#define QKV_LD  3072

typedef __bf16 bf16x8 __attribute__((ext_vector_type(8)));
typedef float  f32x4  __attribute__((ext_vector_type(4)));
typedef u32    u32x4  __attribute__((ext_vector_type(4)));

static __device__ __forceinline__ u16 f2bf(float f){
    union { float f; u32 u; } v; v.f = f;
    return (u16)((v.u + 0x7fffu + ((v.u >> 16) & 1u)) >> 16);
}
static __device__ __forceinline__ u32 pk2(float lo, float hi){
    return (u32)f2bf(lo) | ((u32)f2bf(hi) << 16);
}
static __device__ __forceinline__ bf16x8 ldb8(const u16* p){
    return *reinterpret_cast<const bf16x8*>(p);
}
static __device__ __forceinline__ f32x4 mfma16(bf16x8 a, bf16x8 b, f32x4 c){
    return __builtin_amdgcn_mfma_f32_16x16x32_bf16(a, b, c, 0, 0, 0);
}
static __device__ __forceinline__ void gld16(const void* g, void* l){
    __builtin_amdgcn_global_load_lds((__attribute__((address_space(1))) u32*)g,
                                     (__attribute__((address_space(3))) u32*)l, 16, 0, 0);
}

// ---------------- embedding: x = tok[id]*sqrt(d) + pe[s] ----------------
__global__ __launch_bounds__(256) void k_embed(const int* __restrict__ ids,
        const float* __restrict__ tok, const float* __restrict__ pe,
        float* __restrict__ x){
    int t = blockIdx.x;
    int c = threadIdx.x * 4;
    int id = ids[t];
    int s = t & (SEQ - 1);
    float4 tv = *(const float4*)(tok + (size_t)id * D_MODEL + c);
    float4 pv = *(const float4*)(pe  + (size_t)s  * D_MODEL + c);
    float4 o;
    o.x = tv.x * 32.0f + pv.x;
    o.y = tv.y * 32.0f + pv.y;
    o.z = tv.z * 32.0f + pv.z;
    o.w = tv.w * 32.0f + pv.w;
    *(float4*)(x + (size_t)t * D_MODEL + c) = o;
}

// ---------------- layernorm (f32 in -> bf16 out) ----------------
__global__ __launch_bounds__(256) void k_ln(const float* __restrict__ x,
        const float* __restrict__ g, const float* __restrict__ b,
        u16* __restrict__ out){
    int t = blockIdx.x;
    int tid = threadIdx.x;
    float4 v = *(const float4*)(x + (size_t)t * D_MODEL + tid * 4);
    float s  = v.x + v.y + v.z + v.w;
    float ss = v.x*v.x + v.y*v.y + v.z*v.z + v.w*v.w;
    #pragma unroll
    for (int off = 1; off < 64; off <<= 1){
        s  += __shfl_xor(s, off);
        ss += __shfl_xor(ss, off);
    }
    __shared__ float rs[4], rss[4];
    int w = tid >> 6;
    if ((tid & 63) == 0){ rs[w] = s; rss[w] = ss; }
    __syncthreads();
    s  = rs[0] + rs[1] + rs[2] + rs[3];
    ss = rss[0] + rss[1] + rss[2] + rss[3];
    float mu  = s * (1.0f / D_MODEL);
    float var = ss * (1.0f / D_MODEL) - mu * mu;
    float rstd = rsqrtf(var + 1e-5f);
    float4 gg = *(const float4*)(g + tid * 4);
    float4 bb = *(const float4*)(b + tid * 4);
    uint2 pkv;
    pkv.x = pk2((v.x - mu) * rstd * gg.x + bb.x, (v.y - mu) * rstd * gg.y + bb.y);
    pkv.y = pk2((v.z - mu) * rstd * gg.z + bb.z, (v.w - mu) * rstd * gg.w + bb.w);
    *(uint2*)(out + (size_t)t * D_MODEL + tid * 4) = pkv;
}

// ------- layernorm with fused split-K combine: xn = x + sum(p) + bias -------
template<int NP>
__global__ __launch_bounds__(256) void k_ln_acc(float* __restrict__ x,
        const float* __restrict__ pb,
        const float* __restrict__ bias,
        const float* __restrict__ g, const float* __restrict__ b,
        u16* __restrict__ out){
    int t = blockIdx.x;
    int tid = threadIdx.x;
    size_t idx = (size_t)t * D_MODEL + tid * 4;
    float4 v  = *(const float4*)(x + idx);
    float4 bv = *(const float4*)(bias + tid * 4);
    v.x += bv.x; v.y += bv.y; v.z += bv.z; v.w += bv.w;
    #pragma unroll
    for (int p = 0; p < NP; p++){
        float4 a = *(const float4*)(pb + (size_t)p * NTOK * D_MODEL + idx);
        v.x += a.x; v.y += a.y; v.z += a.z; v.w += a.w;
    }
    *(float4*)(x + idx) = v;
    float s  = v.x + v.y + v.z + v.w;
    float ss = v.x*v.x + v.y*v.y + v.z*v.z + v.w*v.w;
    #pragma unroll
    for (int off = 1; off < 64; off <<= 1){
        s  += __shfl_xor(s, off);
        ss += __shfl_xor(ss, off);
    }
    __shared__ float rs[4], rss[4];
    int w = tid >> 6;
    if ((tid & 63) == 0){ rs[w] = s; rss[w] = ss; }
    __syncthreads();
    s  = rs[0] + rs[1] + rs[2] + rs[3];
    ss = rss[0] + rss[1] + rss[2] + rss[3];
    float mu  = s * (1.0f / D_MODEL);
    float var = ss * (1.0f / D_MODEL) - mu * mu;
    float rstd = rsqrtf(var + 1e-5f);
    float4 gg = *(const float4*)(g + tid * 4);
    float4 bb = *(const float4*)(b + tid * 4);
    uint2 pkv;
    pkv.x = pk2((v.x - mu) * rstd * gg.x + bb.x, (v.y - mu) * rstd * gg.y + bb.y);
    pkv.y = pk2((v.z - mu) * rstd * gg.z + bb.z, (v.w - mu) * rstd * gg.w + bb.w);
    *(uint2*)(out + idx) = pkv;
}

// ------------- Whead f32 -> bf16 cast (same layout [N,K]) -------------
__global__ __launch_bounds__(256) void k_cast(const float* __restrict__ in,
        u16* __restrict__ out){
    size_t i = ((size_t)blockIdx.x * 256 + threadIdx.x) * 8;
    float4 a = *(const float4*)(in + i);
    float4 b = *(const float4*)(in + i + 4);
    u32x4 o;
    o.x = pk2(a.x, a.y); o.y = pk2(a.z, a.w);
    o.z = pk2(b.x, b.y); o.w = pk2(b.z, b.w);
    *(u32x4*)(out + i) = o;
}

// ------------- fused per-layer weight transpose+convert -------------
__global__ __launch_bounds__(256) void k_tconv_fused(
        const float* __restrict__ Wq, const float* __restrict__ Wk,
        const float* __restrict__ Wv, const float* __restrict__ Wo,
        const float* __restrict__ W1, const float* __restrict__ W2,
        u16* __restrict__ wqkvT, u16* __restrict__ woT,
        u16* __restrict__ w1T,   u16* __restrict__ w2T){
    __shared__ float tile[32][33];
    const int id = blockIdx.x;
    const float* in; u16* outp; int R, C, bx, by;
    if (id < 4096){
        int wsel = id >> 10, t = id & 1023;
        bx = t & 31; by = t >> 5; R = 1024; C = 1024;
        in   = (wsel == 0) ? Wq : (wsel == 1) ? Wk : (wsel == 2) ? Wv : Wo;
        outp = (wsel < 3) ? wqkvT + wsel * 1024 * 1024 : woT;
    } else if (id < 8192){
        int t = id - 4096; bx = t & 127; by = t >> 7;
        R = 1024; C = 4096; in = W1; outp = w1T;
    } else {
        int t = id - 8192; bx = t & 31; by = t >> 5;
        R = 4096; C = 1024; in = W2; outp = w2T;
    }
    const int tx = threadIdx.x & 31, ty = threadIdx.x >> 5;
    #pragma unroll
    for (int i = 0; i < 4; i++){
        int r = by * 32 + ty + i * 8;
        tile[ty + i * 8][tx] = in[(size_t)r * C + bx * 32 + tx];
    }
    __syncthreads();
    #pragma unroll
    for (int i = 0; i < 4; i++){
        int c = bx * 32 + ty + i * 8;
        outp[(size_t)c * R + by * 32 + tx] = f2bf(tile[tx][ty + i * 8]);
    }
}

// ---------------- 128-tile deep-pipelined GEMM (layer GEMMs) ----------------
// counted vmcnt(8), raw barriers, both-sides XOR swizzle, setprio.
// 128x128 tile / 4 waves / BK=64, 64 KiB LDS -> 2 blocks/CU.
// VFUSE (QKV only): blocks with n0>=2048 hold V-columns; their output is
// written TRANSPOSED into vt[bh*64+dh][s] (8B packed stores, e-dim = 4
// consecutive tokens = consecutive s) instead of qkv — removes k_vt.
// (A/B r15 vs r16: VFUSE = -4.3 us vs k_vt path.)
template<bool BIAS, bool RELU, bool OBF16, bool AXISM, bool VFUSE>
__global__ __launch_bounds__(256, 2) void k_gemm128p(
    const u16* __restrict__ A, const u16* __restrict__ Bt,
    const float* __restrict__ bias,
    float* __restrict__ outF, u16* __restrict__ outH, u16* __restrict__ vtOut,
    int N, int Kfull, int NXT, int NMT, int NZ)
{
    __shared__ __align__(16) u16 lds[32768];  // 2 slots x (A 8K + B 8K) elems
    const int bid = blockIdx.x;
    const int xcd = bid & 7;
    const int r   = bid >> 3;
    int m_t, n_t, z;
    if constexpr (AXISM) {
        const int mper = NMT >> 3;
        n_t = r % NXT;
        int r2 = r / NXT;
        z = r2 % NZ;
        m_t = xcd * mper + r2 / NZ;
    } else {
        const int nper = NXT >> 3;
        n_t = xcd * nper + r % nper;
        int r2 = r / nper;
        m_t = r2 % NMT;
        z = r2 / NMT;
    }
    const int m0 = m_t * 128;
    const int n0 = n_t * 128;
    const int Kz = Kfull / NZ;
    const int kbeg = z * Kz;
    const int NT = Kz >> 6;

    const int tid  = threadIdx.x;
    const int w    = tid >> 6;
    const int lane = tid & 63;
    const int wr   = w >> 1, wc = w & 1;            // 2m x 2n wave grid
    const int lrow = lane & 15, lkg = lane >> 4;

    // --- staging addressing ---
    const int srow = tid >> 3;                       // 0..31 row within chunk
    const int ssw  = ((tid & 7) ^ (srow & 7)) * 8;   // pre-swizzled 16B slot
    const u16* aSrc0 = A  + (size_t)(m0 +  0 + srow) * Kfull + kbeg + ssw;
    const u16* aSrc1 = A  + (size_t)(m0 + 32 + srow) * Kfull + kbeg + ssw;
    const u16* aSrc2 = A  + (size_t)(m0 + 64 + srow) * Kfull + kbeg + ssw;
    const u16* aSrc3 = A  + (size_t)(m0 + 96 + srow) * Kfull + kbeg + ssw;
    const u16* bSrc0 = Bt + (size_t)(n0 +  0 + srow) * Kfull + kbeg + ssw;
    const u16* bSrc1 = Bt + (size_t)(n0 + 32 + srow) * Kfull + kbeg + ssw;
    const u16* bSrc2 = Bt + (size_t)(n0 + 64 + srow) * Kfull + kbeg + ssw;
    const u16* bSrc3 = Bt + (size_t)(n0 + 96 + srow) * Kfull + kbeg + ssw;

    // --- frag-read addressing ---
    const int sw0 = ((0 + lkg) ^ (lrow & 7)) * 8;
    const int sw1 = ((4 + lkg) ^ (lrow & 7)) * 8;
    const int aBase = (wr * 64 + lrow) * 64;
    const int bBase = (wc * 64 + lrow) * 64 + 8192;

    f32x4 acc[4][4] = {};

    #define STAGE(s, st) do { \
        u16* ab_ = lds + (s) * 16384 + w * 512; \
        const int ko_ = (st) * 64; \
        gld16(aSrc0 + ko_, ab_);              \
        gld16(aSrc1 + ko_, ab_ + 2048);       \
        gld16(aSrc2 + ko_, ab_ + 4096);       \
        gld16(aSrc3 + ko_, ab_ + 6144);       \
        gld16(bSrc0 + ko_, ab_ + 8192);       \
        gld16(bSrc1 + ko_, ab_ + 10240);      \
        gld16(bSrc2 + ko_, ab_ + 12288);      \
        gld16(bSrc3 + ko_, ab_ + 14336);      \
    } while (0)

    STAGE(0, 0);
    STAGE(1, 1);
    asm volatile("s_waitcnt vmcnt(8)" ::: "memory");
    __builtin_amdgcn_s_barrier();
    __builtin_amdgcn_sched_barrier(0);

    for (int t = 0; t < NT; ++t){
        const int s = t & 1;
        const u16* As = lds + s * 16384;

        bf16x8 af0[4], bf0[4];
        #pragma unroll
        for (int i = 0; i < 4; i++) af0[i] = ldb8(As + aBase + i * 1024 + sw0);
        #pragma unroll
        for (int j = 0; j < 4; j++) bf0[j] = ldb8(As + bBase + j * 1024 + sw0);
        __builtin_amdgcn_s_setprio(1);
        #pragma unroll
        for (int i = 0; i < 4; i++)
            #pragma unroll
            for (int j = 0; j < 4; j++)
                acc[i][j] = mfma16(af0[i], bf0[j], acc[i][j]);
        __builtin_amdgcn_s_setprio(0);

        bf16x8 af1[4], bf1[4];
        #pragma unroll
        for (int i = 0; i < 4; i++) af1[i] = ldb8(As + aBase + i * 1024 + sw1);
        #pragma unroll
        for (int j = 0; j < 4; j++) bf1[j] = ldb8(As + bBase + j * 1024 + sw1);
        asm volatile("s_waitcnt lgkmcnt(0)" ::: "memory");
        __builtin_amdgcn_sched_barrier(0);
        __builtin_amdgcn_s_barrier();          // all waves done reading slot s
        __builtin_amdgcn_sched_barrier(0);

        STAGE(s, (t + 2 < NT) ? t + 2 : NT - 1);

        __builtin_amdgcn_s_setprio(1);
        #pragma unroll
        for (int i = 0; i < 4; i++)
            #pragma unroll
            for (int j = 0; j < 4; j++)
                acc[i][j] = mfma16(af1[i], bf1[j], acc[i][j]);
        __builtin_amdgcn_s_setprio(0);

        asm volatile("s_waitcnt vmcnt(8)" ::: "memory");
        __builtin_amdgcn_s_barrier();          // slot s^1 (t+1) now ready
        __builtin_amdgcn_sched_barrier(0);
    }
    #undef STAGE

    float* outFz = outF;
    if (NZ > 1) outFz += (size_t)z * (NMT * 128) * N;

    #pragma unroll
    for (int i = 0; i < 4; i++){
        #pragma unroll
        for (int j = 0; j < 4; j++){
            const int c = n0 + 64 * wc + 16 * j + lrow;
            if (VFUSE && n0 >= 2048) {
                // V columns: write transposed into vt[bh*64+dh][s]
                const int hv = (c - 2048) >> 6, dh = (c - 2048) & 63;
                const int r0 = m0 + 64 * wr + 16 * i + lkg * 4;
                const int bb = r0 >> 10, ss = r0 & 1023;
                uint2 pv;
                pv.x = pk2(acc[i][j][0], acc[i][j][1]);
                pv.y = pk2(acc[i][j][2], acc[i][j][3]);
                *(uint2*)(vtOut + (((size_t)((bb * 16 + hv) * 64 + dh)) << 10) + ss) = pv;
            } else {
                float bv = 0.0f;
                if constexpr (BIAS) bv = bias[c];
                #pragma unroll
                for (int e = 0; e < 4; e++){
                    const int rr = m0 + 64 * wr + 16 * i + lkg * 4 + e;
                    float vv = acc[i][j][e] + bv;
                    if constexpr (RELU) vv = fmaxf(vv, 0.0f);
                    const size_t idx = (size_t)rr * N + c;
                    if constexpr (OBF16) outH[idx] = f2bf(vv);
                    else                 outFz[idx] = vv;
                }
            }
        }
    }
}

// ---------------- head GEMM: 256x256 tile, 512 thr, BK=64, deep pipeline ----
// (validated: 176-182 us, FETCH 115 MB, bank-conflict 0 — best measured head)
__global__ __launch_bounds__(512, 2) void k_gemm_head256(
    const u16* __restrict__ A, const u16* __restrict__ Bt,
    float* __restrict__ out)
{
    __shared__ __align__(16) u16 lds[65536];
    const int bid = blockIdx.x;
    const int swz = (bid & 7) * 125 + (bid >> 3);   // XCD-chunked, 1000%8==0
    const int m0 = (swz >> 3) * 256;                // vocab tile
    const int n0 = (swz & 7) * 256;                 // token tile

    const int tid  = threadIdx.x;
    const int w    = tid >> 6;
    const int lane = tid & 63;
    const int wr   = w >> 2, wc = w & 3;            // 2m x 4n wave grid
    const int lrow = lane & 15, lkg = lane >> 4;

    const int srow = tid >> 3;
    const int ssw  = ((tid & 7) ^ (srow & 7)) * 8;
    const u16* aSrc0 = A  + (size_t)(m0 +   0 + srow) * D_MODEL + ssw;
    const u16* aSrc1 = A  + (size_t)(m0 +  64 + srow) * D_MODEL + ssw;
    const u16* aSrc2 = A  + (size_t)(m0 + 128 + srow) * D_MODEL + ssw;
    const u16* aSrc3 = A  + (size_t)(m0 + 192 + srow) * D_MODEL + ssw;
    const u16* bSrc0 = Bt + (size_t)(n0 +   0 + srow) * D_MODEL + ssw;
    const u16* bSrc1 = Bt + (size_t)(n0 +  64 + srow) * D_MODEL + ssw;
    const u16* bSrc2 = Bt + (size_t)(n0 + 128 + srow) * D_MODEL + ssw;
    const u16* bSrc3 = Bt + (size_t)(n0 + 192 + srow) * D_MODEL + ssw;

    const int sw0 = ((0 + lkg) ^ (lrow & 7)) * 8;
    const int sw1 = ((4 + lkg) ^ (lrow & 7)) * 8;
    const int aBase = (wr * 128 + lrow) * 64;
    const int bBase = (wc * 64  + lrow) * 64;

    f32x4 acc[8][4] = {};

    #define STAGE(s, st) do { \
        u16* ab_ = lds + (s) * 32768 + w * 512; \
        const int ko_ = (st) * 64; \
        gld16(aSrc0 + ko_, ab_);              \
        gld16(aSrc1 + ko_, ab_ + 4096);       \
        gld16(aSrc2 + ko_, ab_ + 8192);       \
        gld16(aSrc3 + ko_, ab_ + 12288);      \
        gld16(bSrc0 + ko_, ab_ + 16384);      \
        gld16(bSrc1 + ko_, ab_ + 20480);      \
        gld16(bSrc2 + ko_, ab_ + 24576);      \
        gld16(bSrc3 + ko_, ab_ + 28672);      \
    } while (0)

    STAGE(0, 0);
    STAGE(1, 1);
    asm volatile("s_waitcnt vmcnt(8)" ::: "memory");
    __builtin_amdgcn_s_barrier();
    __builtin_amdgcn_sched_barrier(0);

    const int NT = D_MODEL / 64;   // 16
    for (int t = 0; t < NT; ++t){
        const int s = t & 1;
        const u16* As = lds + s * 32768;
        const u16* Bs = As + 16384;

        bf16x8 af0[8], bf0[4];
        #pragma unroll
        for (int i = 0; i < 8; i++) af0[i] = ldb8(As + aBase + i * 1024 + sw0);
        #pragma unroll
        for (int j = 0; j < 4; j++) bf0[j] = ldb8(Bs + bBase + j * 1024 + sw0);
        __builtin_amdgcn_s_setprio(1);
        #pragma unroll
        for (int i = 0; i < 8; i++)
            #pragma unroll
            for (int j = 0; j < 4; j++)
                acc[i][j] = mfma16(af0[i], bf0[j], acc[i][j]);
        __builtin_amdgcn_s_setprio(0);

        bf16x8 af1[8], bf1[4];
        #pragma unroll
        for (int i = 0; i < 8; i++) af1[i] = ldb8(As + aBase + i * 1024 + sw1);
        #pragma unroll
        for (int j = 0; j < 4; j++) bf1[j] = ldb8(Bs + bBase + j * 1024 + sw1);
        asm volatile("s_waitcnt lgkmcnt(0)" ::: "memory");
        __builtin_amdgcn_sched_barrier(0);
        __builtin_amdgcn_s_barrier();
        __builtin_amdgcn_sched_barrier(0);

        STAGE(s, (t + 2 < NT) ? t + 2 : NT - 1);

        __builtin_amdgcn_s_setprio(1);
        #pragma unroll
        for (int i = 0; i < 8; i++)
            #pragma unroll
            for (int j = 0; j < 4; j++)
                acc[i][j] = mfma16(af1[i], bf1[j], acc[i][j]);
        __builtin_amdgcn_s_setprio(0);

        asm volatile("s_waitcnt vmcnt(8)" ::: "memory");
        __builtin_amdgcn_s_barrier();
        __builtin_amdgcn_sched_barrier(0);
    }
    #undef STAGE

    #pragma unroll
    for (int i = 0; i < 8; i++){
        const int m = m0 + wr * 128 + i * 16 + lkg * 4;
        #pragma unroll
        for (int j = 0; j < 4; j++){
            const int n = n0 + wc * 64 + j * 16 + lrow;
            float4 st;
            st.x = acc[i][j][0]; st.y = acc[i][j][1];
            st.z = acc[i][j][2]; st.w = acc[i][j][3];
            *(float4*)(out + (size_t)n * NVOCAB + m) = st;
        }
    }
}

// ---------------- flash attention: 1 wave per 16-row q-tile, KVBLK=64 -------
__global__ __launch_bounds__(256) void k_attn(const u16* __restrict__ qkv,
        const u16* __restrict__ vt, u16* __restrict__ ctx){
    const int wid  = (blockIdx.x << 2) + (threadIdx.x >> 6);
    const int lane = threadIdx.x & 63;
    const int qt = wid & 63;
    const int h  = (wid >> 6) & 15;
    const int b  = wid >> 10;
    const int q0 = qt * 16;
    const int lrow = lane & 15, lkg = lane >> 4;

    __shared__ __align__(16) u16 plds_all[4][16][72]; // 144B rows, 16B-aligned
    u16 (*plds)[72] = plds_all[threadIdx.x >> 6];

    const u16* qbase = qkv + (size_t)(b * SEQ + q0 + lrow) * QKV_LD + h * DKH + 8 * lkg;
    const bf16x8 qf0 = ldb8(qbase);
    const bf16x8 qf1 = ldb8(qbase + 32);

    float mr[4], lsum[4];
    f32x4 acc[4] = {};
    #pragma unroll
    for (int e = 0; e < 4; e++){ mr[e] = -1e30f; lsum[e] = 0.0f; }

    const int nkb = (q0 >> 6) + 1;
    const u16* kbase  = qkv + (size_t)(b * SEQ) * QKV_LD + 1024 + h * DKH;
    const u16* vtbase = vt + (size_t)((b * NHEADS + h) * DKH) * SEQ;

    for (int kb = 0; kb < nkb; ++kb){
        const int kc = kb * 64;
        f32x4 sg[4] = {};
        const u16* kp = kbase + (size_t)(kc + lrow) * QKV_LD + 8 * lkg;
        bf16x8 ka[4], kbv[4];
        #pragma unroll
        for (int g = 0; g < 4; g++){
            const u16* p = kp + (size_t)(16 * g) * QKV_LD;
            ka[g]  = ldb8(p);
            kbv[g] = ldb8(p + 32);
        }
        __builtin_amdgcn_s_setprio(1);
        #pragma unroll
        for (int g = 0; g < 4; g++){
            sg[g] = mfma16(qf0, ka[g],  sg[g]);
            sg[g] = mfma16(qf1, kbv[g], sg[g]);
        }
        __builtin_amdgcn_s_setprio(0);

        #pragma unroll
        for (int e = 0; e < 4; e++){
            const int row = q0 + lkg * 4 + e;
            float v0 = (kc      + lrow > row) ? -1e30f : sg[0][e] * 0.125f;
            float v1 = (kc + 16 + lrow > row) ? -1e30f : sg[1][e] * 0.125f;
            float v2 = (kc + 32 + lrow > row) ? -1e30f : sg[2][e] * 0.125f;
            float v3 = (kc + 48 + lrow > row) ? -1e30f : sg[3][e] * 0.125f;
            float t = fmaxf(fmaxf(v0, v1), fmaxf(v2, v3));
            t = fmaxf(t, __shfl_xor(t, 1));
            t = fmaxf(t, __shfl_xor(t, 2));
            t = fmaxf(t, __shfl_xor(t, 4));
            t = fmaxf(t, __shfl_xor(t, 8));
            const float mn = fmaxf(mr[e], t);
            const float al = __expf(mr[e] - mn);
            const float p0 = __expf(v0 - mn);
            const float p1 = __expf(v1 - mn);
            const float p2 = __expf(v2 - mn);
            const float p3 = __expf(v3 - mn);
            float rsum = (p0 + p1) + (p2 + p3);
            rsum += __shfl_xor(rsum, 1);
            rsum += __shfl_xor(rsum, 2);
            rsum += __shfl_xor(rsum, 4);
            rsum += __shfl_xor(rsum, 8);
            lsum[e] = lsum[e] * al + rsum;
            mr[e] = mn;
            #pragma unroll
            for (int nt = 0; nt < 4; nt++) acc[nt][e] *= al;
            u16* prow = plds[lkg * 4 + e];
            prow[lrow]      = f2bf(p0);
            prow[16 + lrow] = f2bf(p1);
            prow[32 + lrow] = f2bf(p2);
            prow[48 + lrow] = f2bf(p3);
        }
        asm volatile("" ::: "memory"); // keep P writes before the frag read
        const bf16x8 pf0 = ldb8(&plds[lrow][8 * lkg]);
        const bf16x8 pf1 = ldb8(&plds[lrow][32 + 8 * lkg]);
        __builtin_amdgcn_s_setprio(1);
        #pragma unroll
        for (int nt = 0; nt < 4; nt++){
            const u16* vp = vtbase + (size_t)(16 * nt + lrow) * SEQ + kc + 8 * lkg;
            acc[nt] = mfma16(pf0, ldb8(vp),      acc[nt]);
            acc[nt] = mfma16(pf1, ldb8(vp + 32), acc[nt]);
        }
        __builtin_amdgcn_s_setprio(0);
    }
    #pragma unroll
    for (int nt = 0; nt < 4; nt++){
        #pragma unroll
        for (int e = 0; e < 4; e++){
            const int r = q0 + lkg * 4 + e;
            ctx[(size_t)(b * SEQ + r) * D_MODEL + h * DKH + 16 * nt + lrow] =
                f2bf(acc[nt][e] / lsum[e]);
        }
    }
}

// ---------------- launcher ----------------
extern "C" void kernel_launch(void* const* d_in, const int* in_sizes, int n_in,
                              void* d_out, int out_size, void* d_ws, size_t ws_size,
                              hipStream_t stream){
    const int*   ids  = (const int*)  d_in[0];
    const float* tok  = (const float*)d_in[1];
    const float* pe   = (const float*)d_in[2];
    const float* Wq   = (const float*)d_in[3];
    const float* Wk   = (const float*)d_in[4];
    const float* Wv   = (const float*)d_in[5];
    const float* Wo   = (const float*)d_in[6];
    const float* bo   = (const float*)d_in[7];
    const float* W1   = (const float*)d_in[8];
    const float* b1   = (const float*)d_in[9];
    const float* W2   = (const float*)d_in[10];
    const float* b2   = (const float*)d_in[11];
    const float* ln1g = (const float*)d_in[12];
    const float* ln1b = (const float*)d_in[13];
    const float* ln2g = (const float*)d_in[14];
    const float* ln2b = (const float*)d_in[15];
    const float* lnfg = (const float*)d_in[16];
    const float* lnfb = (const float*)d_in[17];
    const float* Wh   = (const float*)d_in[18];
    float* out = (float*)d_out;

    char* ws = (char*)d_ws;
    size_t off = 0;
    auto alloc = [&](size_t bytes) -> void* {
        void* p = ws + off;
        off += (bytes + 255) & ~(size_t)255;
        return p;
    };
    float* x     = (float*)alloc((size_t)NTOK * D_MODEL * 4);   // 8 MB
    u16*   hbuf  = (u16*)  alloc((size_t)NTOK * D_MODEL * 2);   // 4 MB
    u16*   qkv   = (u16*)  alloc((size_t)NTOK * QKV_LD  * 2);   // 12 MB
    u16*   vt    = (u16*)  alloc((size_t)NTOK * D_MODEL * 2);   // 4 MB
    u16*   ctx   = (u16*)  alloc((size_t)NTOK * D_MODEL * 2);   // 4 MB
    u16*   f1    = (u16*)  alloc((size_t)NTOK * DFF     * 2);   // 16 MB
    float* pbuf  = (float*)alloc((size_t)2 * NTOK * D_MODEL * 4); // 16 MB (2 split-K partials)
    u16*   wqkvT = (u16*)  alloc((size_t)QKV_LD * D_MODEL * 2); // 6 MB
    u16*   woT   = (u16*)  alloc((size_t)D_MODEL * D_MODEL * 2);// 2 MB
    u16*   w1T   = (u16*)  alloc((size_t)DFF * D_MODEL * 2);    // 8 MB
    u16*   w2T   = (u16*)  alloc((size_t)D_MODEL * DFF * 2);    // 8 MB
    u16*   whB   = (u16*)  alloc((size_t)NVOCAB * D_MODEL * 2); // 65.5 MB
    (void)ws_size; (void)in_sizes; (void)n_in; (void)out_size;

    k_embed<<<NTOK, 256, 0, stream>>>(ids, tok, pe, x);
    k_cast<<<(NVOCAB * D_MODEL) / (256 * 8), 256, 0, stream>>>(Wh, whB);

    for (int l = 0; l < NLAYERS; l++){
        const size_t wdd = (size_t)l * D_MODEL * D_MODEL;
        const size_t wdf = (size_t)l * D_MODEL * DFF;
        k_tconv_fused<<<12288, 256, 0, stream>>>(
            Wq + wdd, Wk + wdd, Wv + wdd, Wo + wdd, W1 + wdf, W2 + wdf,
            wqkvT, woT, w1T, w2T);

        if (l == 0)
            k_ln<<<NTOK, 256, 0, stream>>>(x, ln1g, ln1b, hbuf);
        else
            k_ln_acc<2><<<NTOK, 256, 0, stream>>>(x, pbuf, b2 + (l - 1) * D_MODEL,
                ln1g + l * D_MODEL, ln1b + l * D_MODEL, hbuf);

        // QKV GEMM (+fused V-transpose): grid 384 = 8 xcd * 3 n * 16 m
        k_gemm128p<false, false, true, false, true><<<384, 256, 0, stream>>>(
            hbuf, wqkvT, nullptr, nullptr, qkv, vt, QKV_LD, D_MODEL, 24, 16, 1);
        k_attn<<<512, 256, 0, stream>>>(qkv, vt, ctx);

        // Wo GEMM split-K=2: grid 256
        k_gemm128p<false, false, false, true, false><<<256, 256, 0, stream>>>(
            ctx, woT, nullptr, pbuf, nullptr, nullptr, D_MODEL, D_MODEL, 8, 16, 2);
        k_ln_acc<2><<<NTOK, 256, 0, stream>>>(x, pbuf, bo + l * D_MODEL,
            ln2g + l * D_MODEL, ln2b + l * D_MODEL, hbuf);

        // W1 GEMM: grid 512 = 8 xcd * 4 n * 16 m
        k_gemm128p<true, true, true, false, false><<<512, 256, 0, stream>>>(
            hbuf, w1T, b1 + l * DFF, nullptr, f1, nullptr, DFF, D_MODEL, 32, 16, 1);
        // W2 GEMM split-K=2: grid 256 (NZ4 measured +9.7 us — reverted)
        k_gemm128p<false, false, false, true, false><<<256, 256, 0, stream>>>(
            f1, w2T, nullptr, pbuf, nullptr, nullptr, D_MODEL, DFF, 8, 16, 2);
    }

    k_ln_acc<2><<<NTOK, 256, 0, stream>>>(x, pbuf, b2 + 3 * D_MODEL,
        lnfg, lnfb, hbuf);
    // head GEMM: k_gemm_head256 — best measured (176-182 us, FETCH 115MB).
    k_gemm_head256<<<1000, 512, 0, stream>>>(whB, hbuf, out);
}

// Round 18
// 907.408 us; speedup vs baseline: 1.0214x; 1.0050x over previous
//
#include <hip/hip_runtime.h>
#include <stdint.h>

typedef unsigned short u16;
typedef unsigned int   u32;

#define D_MODEL 1024
#define NHEADS  16
#define DKH     64
#define DFF     4096
#define NLAYERS 4
#define BATCH   2
#define SEQ     1024
#define NTOK    (BATCH*SEQ)
#define NVOCAB  32000
#define QKV_LD  3072

typedef __bf16 bf16x8 __attribute__((ext_vector_type(8)));
typedef float  f32x4  __attribute__((ext_vector_type(4)));
typedef u32    u32x4  __attribute__((ext_vector_type(4)));

static __device__ __forceinline__ u16 f2bf(float f){
    union { float f; u32 u; } v; v.f = f;
    return (u16)((v.u + 0x7fffu + ((v.u >> 16) & 1u)) >> 16);
}
static __device__ __forceinline__ u32 pk2(float lo, float hi){
    return (u32)f2bf(lo) | ((u32)f2bf(hi) << 16);
}
static __device__ __forceinline__ bf16x8 ldb8(const u16* p){
    return *reinterpret_cast<const bf16x8*>(p);
}
static __device__ __forceinline__ f32x4 mfma16(bf16x8 a, bf16x8 b, f32x4 c){
    return __builtin_amdgcn_mfma_f32_16x16x32_bf16(a, b, c, 0, 0, 0);
}
static __device__ __forceinline__ void gld16(const void* g, void* l){
    __builtin_amdgcn_global_load_lds((__attribute__((address_space(1))) u32*)g,
                                     (__attribute__((address_space(3))) u32*)l, 16, 0, 0);
}

// ---------------- embedding: x = tok[id]*sqrt(d) + pe[s] ----------------
__global__ __launch_bounds__(256) void k_embed(const int* __restrict__ ids,
        const float* __restrict__ tok, const float* __restrict__ pe,
        float* __restrict__ x){
    int t = blockIdx.x;
    int c = threadIdx.x * 4;
    int id = ids[t];
    int s = t & (SEQ - 1);
    float4 tv = *(const float4*)(tok + (size_t)id * D_MODEL + c);
    float4 pv = *(const float4*)(pe  + (size_t)s  * D_MODEL + c);
    float4 o;
    o.x = tv.x * 32.0f + pv.x;
    o.y = tv.y * 32.0f + pv.y;
    o.z = tv.z * 32.0f + pv.z;
    o.w = tv.w * 32.0f + pv.w;
    *(float4*)(x + (size_t)t * D_MODEL + c) = o;
}

// ---------------- layernorm (f32 in -> bf16 out) ----------------
__global__ __launch_bounds__(256) void k_ln(const float* __restrict__ x,
        const float* __restrict__ g, const float* __restrict__ b,
        u16* __restrict__ out){
    int t = blockIdx.x;
    int tid = threadIdx.x;
    float4 v = *(const float4*)(x + (size_t)t * D_MODEL + tid * 4);
    float s  = v.x + v.y + v.z + v.w;
    float ss = v.x*v.x + v.y*v.y + v.z*v.z + v.w*v.w;
    #pragma unroll
    for (int off = 1; off < 64; off <<= 1){
        s  += __shfl_xor(s, off);
        ss += __shfl_xor(ss, off);
    }
    __shared__ float rs[4], rss[4];
    int w = tid >> 6;
    if ((tid & 63) == 0){ rs[w] = s; rss[w] = ss; }
    __syncthreads();
    s  = rs[0] + rs[1] + rs[2] + rs[3];
    ss = rss[0] + rss[1] + rss[2] + rss[3];
    float mu  = s * (1.0f / D_MODEL);
    float var = ss * (1.0f / D_MODEL) - mu * mu;
    float rstd = rsqrtf(var + 1e-5f);
    float4 gg = *(const float4*)(g + tid * 4);
    float4 bb = *(const float4*)(b + tid * 4);
    uint2 pkv;
    pkv.x = pk2((v.x - mu) * rstd * gg.x + bb.x, (v.y - mu) * rstd * gg.y + bb.y);
    pkv.y = pk2((v.z - mu) * rstd * gg.z + bb.z, (v.w - mu) * rstd * gg.w + bb.w);
    *(uint2*)(out + (size_t)t * D_MODEL + tid * 4) = pkv;
}

// ------- layernorm with fused split-K combine: xn = x + sum(p) + bias -------
template<int NP>
__global__ __launch_bounds__(256) void k_ln_acc(float* __restrict__ x,
        const float* __restrict__ pb,
        const float* __restrict__ bias,
        const float* __restrict__ g, const float* __restrict__ b,
        u16* __restrict__ out){
    int t = blockIdx.x;
    int tid = threadIdx.x;
    size_t idx = (size_t)t * D_MODEL + tid * 4;
    float4 v  = *(const float4*)(x + idx);
    float4 bv = *(const float4*)(bias + tid * 4);
    v.x += bv.x; v.y += bv.y; v.z += bv.z; v.w += bv.w;
    #pragma unroll
    for (int p = 0; p < NP; p++){
        float4 a = *(const float4*)(pb + (size_t)p * NTOK * D_MODEL + idx);
        v.x += a.x; v.y += a.y; v.z += a.z; v.w += a.w;
    }
    *(float4*)(x + idx) = v;
    float s  = v.x + v.y + v.z + v.w;
    float ss = v.x*v.x + v.y*v.y + v.z*v.z + v.w*v.w;
    #pragma unroll
    for (int off = 1; off < 64; off <<= 1){
        s  += __shfl_xor(s, off);
        ss += __shfl_xor(ss, off);
    }
    __shared__ float rs[4], rss[4];
    int w = tid >> 6;
    if ((tid & 63) == 0){ rs[w] = s; rss[w] = ss; }
    __syncthreads();
    s  = rs[0] + rs[1] + rs[2] + rs[3];
    ss = rss[0] + rss[1] + rss[2] + rss[3];
    float mu  = s * (1.0f / D_MODEL);
    float var = ss * (1.0f / D_MODEL) - mu * mu;
    float rstd = rsqrtf(var + 1e-5f);
    float4 gg = *(const float4*)(g + tid * 4);
    float4 bb = *(const float4*)(b + tid * 4);
    uint2 pkv;
    pkv.x = pk2((v.x - mu) * rstd * gg.x + bb.x, (v.y - mu) * rstd * gg.y + bb.y);
    pkv.y = pk2((v.z - mu) * rstd * gg.z + bb.z, (v.w - mu) * rstd * gg.w + bb.w);
    *(uint2*)(out + idx) = pkv;
}

// ------------- fused weight transpose+convert (vectorized) + optional cast ---
// 32x64 f32 tiles: float4 reads (16B/lane), LDS [32][65] (<=2-way banks, free),
// packed uint2 transposed writes (8B/lane, 64B-granule coalesced).
// Per layer: 6144 blocks (2048 qkv/o + 2048 W1 + 2048 W2).
// Layer 0 appends 16000 cast blocks (id>=6144): Wh f32 -> whB bf16 — the
// 196 MB cast streams concurrently with the transposes instead of serially.
__global__ __launch_bounds__(256) void k_tconv_fused(
        const float* __restrict__ Wq, const float* __restrict__ Wk,
        const float* __restrict__ Wv, const float* __restrict__ Wo,
        const float* __restrict__ W1, const float* __restrict__ W2,
        u16* __restrict__ wqkvT, u16* __restrict__ woT,
        u16* __restrict__ w1T,   u16* __restrict__ w2T,
        const float* __restrict__ WhS, u16* __restrict__ whD){
    const int id  = blockIdx.x;
    const int tid = threadIdx.x;
    if (id >= 6144){
        size_t i = ((size_t)(id - 6144) * 256 + tid) * 8;
        float4 a = *(const float4*)(WhS + i);
        float4 b = *(const float4*)(WhS + i + 4);
        u32x4 o;
        o.x = pk2(a.x, a.y); o.y = pk2(a.z, a.w);
        o.z = pk2(b.x, b.y); o.w = pk2(b.z, b.w);
        *(u32x4*)(whD + i) = o;
        return;
    }
    __shared__ float tile[32][65];
    const float* in; u16* outp; int Rr, Cc, bx, by;
    if (id < 2048){
        int wsel = id >> 9, t = id & 511;
        bx = t & 15; by = t >> 4; Rr = 1024; Cc = 1024;
        in   = (wsel == 0) ? Wq : (wsel == 1) ? Wk : (wsel == 2) ? Wv : Wo;
        outp = (wsel < 3) ? wqkvT + wsel * 1024 * 1024 : woT;
    } else if (id < 4096){
        int t = id - 2048; bx = t & 63; by = t >> 6; Rr = 1024; Cc = 4096;
        in = W1; outp = w1T;
    } else {
        int t = id - 4096; bx = t & 15; by = t >> 4; Rr = 4096; Cc = 1024;
        in = W2; outp = w2T;
    }
    const int rt = tid >> 4, cq = tid & 15;
    #pragma unroll
    for (int i = 0; i < 2; i++){
        int row = by * 32 + rt + i * 16;
        float4 v = *(const float4*)(in + (size_t)row * Cc + bx * 64 + cq * 4);
        tile[rt + i * 16][cq * 4 + 0] = v.x;
        tile[rt + i * 16][cq * 4 + 1] = v.y;
        tile[rt + i * 16][cq * 4 + 2] = v.z;
        tile[rt + i * 16][cq * 4 + 3] = v.w;
    }
    __syncthreads();
    const int cW = tid >> 3, rg = tid & 7;
    #pragma unroll
    for (int i = 0; i < 2; i++){
        int c = bx * 64 + cW + i * 32;
        float a0 = tile[rg * 4 + 0][cW + i * 32];
        float a1 = tile[rg * 4 + 1][cW + i * 32];
        float a2 = tile[rg * 4 + 2][cW + i * 32];
        float a3 = tile[rg * 4 + 3][cW + i * 32];
        uint2 pv;
        pv.x = pk2(a0, a1);
        pv.y = pk2(a2, a3);
        *(uint2*)(outp + (size_t)c * Rr + by * 32 + rg * 4) = pv;
    }
}

// ---------------- 128-tile deep-pipelined GEMM (layer GEMMs) ----------------
// counted vmcnt(8), raw barriers, both-sides XOR swizzle, setprio.
// 128x128 tile / 4 waves / BK=64, 64 KiB LDS -> 2 blocks/CU.
// VFUSE (QKV only): blocks with n0>=2048 hold V-columns; their output is
// written TRANSPOSED into vt[bh*64+dh][s] — removes k_vt (A/B: -4.3 us).
template<bool BIAS, bool RELU, bool OBF16, bool AXISM, bool VFUSE>
__global__ __launch_bounds__(256, 2) void k_gemm128p(
    const u16* __restrict__ A, const u16* __restrict__ Bt,
    const float* __restrict__ bias,
    float* __restrict__ outF, u16* __restrict__ outH, u16* __restrict__ vtOut,
    int N, int Kfull, int NXT, int NMT, int NZ)
{
    __shared__ __align__(16) u16 lds[32768];  // 2 slots x (A 8K + B 8K) elems
    const int bid = blockIdx.x;
    const int xcd = bid & 7;
    const int r   = bid >> 3;
    int m_t, n_t, z;
    if constexpr (AXISM) {
        const int mper = NMT >> 3;
        n_t = r % NXT;
        int r2 = r / NXT;
        z = r2 % NZ;
        m_t = xcd * mper + r2 / NZ;
    } else {
        const int nper = NXT >> 3;
        n_t = xcd * nper + r % nper;
        int r2 = r / nper;
        m_t = r2 % NMT;
        z = r2 / NMT;
    }
    const int m0 = m_t * 128;
    const int n0 = n_t * 128;
    const int Kz = Kfull / NZ;
    const int kbeg = z * Kz;
    const int NT = Kz >> 6;

    const int tid  = threadIdx.x;
    const int w    = tid >> 6;
    const int lane = tid & 63;
    const int wr   = w >> 1, wc = w & 1;            // 2m x 2n wave grid
    const int lrow = lane & 15, lkg = lane >> 4;

    // --- staging addressing ---
    const int srow = tid >> 3;                       // 0..31 row within chunk
    const int ssw  = ((tid & 7) ^ (srow & 7)) * 8;   // pre-swizzled 16B slot
    const u16* aSrc0 = A  + (size_t)(m0 +  0 + srow) * Kfull + kbeg + ssw;
    const u16* aSrc1 = A  + (size_t)(m0 + 32 + srow) * Kfull + kbeg + ssw;
    const u16* aSrc2 = A  + (size_t)(m0 + 64 + srow) * Kfull + kbeg + ssw;
    const u16* aSrc3 = A  + (size_t)(m0 + 96 + srow) * Kfull + kbeg + ssw;
    const u16* bSrc0 = Bt + (size_t)(n0 +  0 + srow) * Kfull + kbeg + ssw;
    const u16* bSrc1 = Bt + (size_t)(n0 + 32 + srow) * Kfull + kbeg + ssw;
    const u16* bSrc2 = Bt + (size_t)(n0 + 64 + srow) * Kfull + kbeg + ssw;
    const u16* bSrc3 = Bt + (size_t)(n0 + 96 + srow) * Kfull + kbeg + ssw;

    // --- frag-read addressing ---
    const int sw0 = ((0 + lkg) ^ (lrow & 7)) * 8;
    const int sw1 = ((4 + lkg) ^ (lrow & 7)) * 8;
    const int aBase = (wr * 64 + lrow) * 64;
    const int bBase = (wc * 64 + lrow) * 64 + 8192;

    f32x4 acc[4][4] = {};

    #define STAGE(s, st) do { \
        u16* ab_ = lds + (s) * 16384 + w * 512; \
        const int ko_ = (st) * 64; \
        gld16(aSrc0 + ko_, ab_);              \
        gld16(aSrc1 + ko_, ab_ + 2048);       \
        gld16(aSrc2 + ko_, ab_ + 4096);       \
        gld16(aSrc3 + ko_, ab_ + 6144);       \
        gld16(bSrc0 + ko_, ab_ + 8192);       \
        gld16(bSrc1 + ko_, ab_ + 10240);      \
        gld16(bSrc2 + ko_, ab_ + 12288);      \
        gld16(bSrc3 + ko_, ab_ + 14336);      \
    } while (0)

    STAGE(0, 0);
    STAGE(1, 1);
    asm volatile("s_waitcnt vmcnt(8)" ::: "memory");
    __builtin_amdgcn_s_barrier();
    __builtin_amdgcn_sched_barrier(0);

    for (int t = 0; t < NT; ++t){
        const int s = t & 1;
        const u16* As = lds + s * 16384;

        bf16x8 af0[4], bf0[4];
        #pragma unroll
        for (int i = 0; i < 4; i++) af0[i] = ldb8(As + aBase + i * 1024 + sw0);
        #pragma unroll
        for (int j = 0; j < 4; j++) bf0[j] = ldb8(As + bBase + j * 1024 + sw0);
        __builtin_amdgcn_s_setprio(1);
        #pragma unroll
        for (int i = 0; i < 4; i++)
            #pragma unroll
            for (int j = 0; j < 4; j++)
                acc[i][j] = mfma16(af0[i], bf0[j], acc[i][j]);
        __builtin_amdgcn_s_setprio(0);

        bf16x8 af1[4], bf1[4];
        #pragma unroll
        for (int i = 0; i < 4; i++) af1[i] = ldb8(As + aBase + i * 1024 + sw1);
        #pragma unroll
        for (int j = 0; j < 4; j++) bf1[j] = ldb8(As + bBase + j * 1024 + sw1);
        asm volatile("s_waitcnt lgkmcnt(0)" ::: "memory");
        __builtin_amdgcn_sched_barrier(0);
        __builtin_amdgcn_s_barrier();          // all waves done reading slot s
        __builtin_amdgcn_sched_barrier(0);

        STAGE(s, (t + 2 < NT) ? t + 2 : NT - 1);

        __builtin_amdgcn_s_setprio(1);
        #pragma unroll
        for (int i = 0; i < 4; i++)
            #pragma unroll
            for (int j = 0; j < 4; j++)
                acc[i][j] = mfma16(af1[i], bf1[j], acc[i][j]);
        __builtin_amdgcn_s_setprio(0);

        asm volatile("s_waitcnt vmcnt(8)" ::: "memory");
        __builtin_amdgcn_s_barrier();          // slot s^1 (t+1) now ready
        __builtin_amdgcn_sched_barrier(0);
    }
    #undef STAGE

    float* outFz = outF;
    if (NZ > 1) outFz += (size_t)z * (NMT * 128) * N;

    #pragma unroll
    for (int i = 0; i < 4; i++){
        #pragma unroll
        for (int j = 0; j < 4; j++){
            const int c = n0 + 64 * wc + 16 * j + lrow;
            if (VFUSE && n0 >= 2048) {
                // V columns: write transposed into vt[bh*64+dh][s]
                const int hv = (c - 2048) >> 6, dh = (c - 2048) & 63;
                const int r0 = m0 + 64 * wr + 16 * i + lkg * 4;
                const int bb = r0 >> 10, ss = r0 & 1023;
                uint2 pv;
                pv.x = pk2(acc[i][j][0], acc[i][j][1]);
                pv.y = pk2(acc[i][j][2], acc[i][j][3]);
                *(uint2*)(vtOut + (((size_t)((bb * 16 + hv) * 64 + dh)) << 10) + ss) = pv;
            } else {
                float bv = 0.0f;
                if constexpr (BIAS) bv = bias[c];
                #pragma unroll
                for (int e = 0; e < 4; e++){
                    const int rr = m0 + 64 * wr + 16 * i + lkg * 4 + e;
                    float vv = acc[i][j][e] + bv;
                    if constexpr (RELU) vv = fmaxf(vv, 0.0f);
                    const size_t idx = (size_t)rr * N + c;
                    if constexpr (OBF16) outH[idx] = f2bf(vv);
                    else                 outFz[idx] = vv;
                }
            }
        }
    }
}

// ---------------- head GEMM: 256x256 tile, 512 thr, BK=64, deep pipeline ----
// (validated: 176-182 us, FETCH 115 MB, bank-conflict 0 — best measured head)
__global__ __launch_bounds__(512, 2) void k_gemm_head256(
    const u16* __restrict__ A, const u16* __restrict__ Bt,
    float* __restrict__ out)
{
    __shared__ __align__(16) u16 lds[65536];
    const int bid = blockIdx.x;
    const int swz = (bid & 7) * 125 + (bid >> 3);   // XCD-chunked, 1000%8==0
    const int m0 = (swz >> 3) * 256;                // vocab tile
    const int n0 = (swz & 7) * 256;                 // token tile

    const int tid  = threadIdx.x;
    const int w    = tid >> 6;
    const int lane = tid & 63;
    const int wr   = w >> 2, wc = w & 3;            // 2m x 4n wave grid
    const int lrow = lane & 15, lkg = lane >> 4;

    const int srow = tid >> 3;
    const int ssw  = ((tid & 7) ^ (srow & 7)) * 8;
    const u16* aSrc0 = A  + (size_t)(m0 +   0 + srow) * D_MODEL + ssw;
    const u16* aSrc1 = A  + (size_t)(m0 +  64 + srow) * D_MODEL + ssw;
    const u16* aSrc2 = A  + (size_t)(m0 + 128 + srow) * D_MODEL + ssw;
    const u16* aSrc3 = A  + (size_t)(m0 + 192 + srow) * D_MODEL + ssw;
    const u16* bSrc0 = Bt + (size_t)(n0 +   0 + srow) * D_MODEL + ssw;
    const u16* bSrc1 = Bt + (size_t)(n0 +  64 + srow) * D_MODEL + ssw;
    const u16* bSrc2 = Bt + (size_t)(n0 + 128 + srow) * D_MODEL + ssw;
    const u16* bSrc3 = Bt + (size_t)(n0 + 192 + srow) * D_MODEL + ssw;

    const int sw0 = ((0 + lkg) ^ (lrow & 7)) * 8;
    const int sw1 = ((4 + lkg) ^ (lrow & 7)) * 8;
    const int aBase = (wr * 128 + lrow) * 64;
    const int bBase = (wc * 64  + lrow) * 64;

    f32x4 acc[8][4] = {};

    #define STAGE(s, st) do { \
        u16* ab_ = lds + (s) * 32768 + w * 512; \
        const int ko_ = (st) * 64; \
        gld16(aSrc0 + ko_, ab_);              \
        gld16(aSrc1 + ko_, ab_ + 4096);       \
        gld16(aSrc2 + ko_, ab_ + 8192);       \
        gld16(aSrc3 + ko_, ab_ + 12288);      \
        gld16(bSrc0 + ko_, ab_ + 16384);      \
        gld16(bSrc1 + ko_, ab_ + 20480);      \
        gld16(bSrc2 + ko_, ab_ + 24576);      \
        gld16(bSrc3 + ko_, ab_ + 28672);      \
    } while (0)

    STAGE(0, 0);
    STAGE(1, 1);
    asm volatile("s_waitcnt vmcnt(8)" ::: "memory");
    __builtin_amdgcn_s_barrier();
    __builtin_amdgcn_sched_barrier(0);

    const int NT = D_MODEL / 64;   // 16
    for (int t = 0; t < NT; ++t){
        const int s = t & 1;
        const u16* As = lds + s * 32768;
        const u16* Bs = As + 16384;

        bf16x8 af0[8], bf0[4];
        #pragma unroll
        for (int i = 0; i < 8; i++) af0[i] = ldb8(As + aBase + i * 1024 + sw0);
        #pragma unroll
        for (int j = 0; j < 4; j++) bf0[j] = ldb8(Bs + bBase + j * 1024 + sw0);
        __builtin_amdgcn_s_setprio(1);
        #pragma unroll
        for (int i = 0; i < 8; i++)
            #pragma unroll
            for (int j = 0; j < 4; j++)
                acc[i][j] = mfma16(af0[i], bf0[j], acc[i][j]);
        __builtin_amdgcn_s_setprio(0);

        bf16x8 af1[8], bf1[4];
        #pragma unroll
        for (int i = 0; i < 8; i++) af1[i] = ldb8(As + aBase + i * 1024 + sw1);
        #pragma unroll
        for (int j = 0; j < 4; j++) bf1[j] = ldb8(Bs + bBase + j * 1024 + sw1);
        asm volatile("s_waitcnt lgkmcnt(0)" ::: "memory");
        __builtin_amdgcn_sched_barrier(0);
        __builtin_amdgcn_s_barrier();
        __builtin_amdgcn_sched_barrier(0);

        STAGE(s, (t + 2 < NT) ? t + 2 : NT - 1);

        __builtin_amdgcn_s_setprio(1);
        #pragma unroll
        for (int i = 0; i < 8; i++)
            #pragma unroll
            for (int j = 0; j < 4; j++)
                acc[i][j] = mfma16(af1[i], bf1[j], acc[i][j]);
        __builtin_amdgcn_s_setprio(0);

        asm volatile("s_waitcnt vmcnt(8)" ::: "memory");
        __builtin_amdgcn_s_barrier();
        __builtin_amdgcn_sched_barrier(0);
    }
    #undef STAGE

    #pragma unroll
    for (int i = 0; i < 8; i++){
        const int m = m0 + wr * 128 + i * 16 + lkg * 4;
        #pragma unroll
        for (int j = 0; j < 4; j++){
            const int n = n0 + wc * 64 + j * 16 + lrow;
            float4 st;
            st.x = acc[i][j][0]; st.y = acc[i][j][1];
            st.z = acc[i][j][2]; st.w = acc[i][j][3];
            *(float4*)(out + (size_t)n * NVOCAB + m) = st;
        }
    }
}

// ---------------- flash attention: 1 wave per 16-row q-tile, KVBLK=64 -------
__global__ __launch_bounds__(256) void k_attn(const u16* __restrict__ qkv,
        const u16* __restrict__ vt, u16* __restrict__ ctx){
    const int wid  = (blockIdx.x << 2) + (threadIdx.x >> 6);
    const int lane = threadIdx.x & 63;
    const int qt = wid & 63;
    const int h  = (wid >> 6) & 15;
    const int b  = wid >> 10;
    const int q0 = qt * 16;
    const int lrow = lane & 15, lkg = lane >> 4;

    __shared__ __align__(16) u16 plds_all[4][16][72]; // 144B rows, 16B-aligned
    u16 (*plds)[72] = plds_all[threadIdx.x >> 6];

    const u16* qbase = qkv + (size_t)(b * SEQ + q0 + lrow) * QKV_LD + h * DKH + 8 * lkg;
    const bf16x8 qf0 = ldb8(qbase);
    const bf16x8 qf1 = ldb8(qbase + 32);

    float mr[4], lsum[4];
    f32x4 acc[4] = {};
    #pragma unroll
    for (int e = 0; e < 4; e++){ mr[e] = -1e30f; lsum[e] = 0.0f; }

    const int nkb = (q0 >> 6) + 1;
    const u16* kbase  = qkv + (size_t)(b * SEQ) * QKV_LD + 1024 + h * DKH;
    const u16* vtbase = vt + (size_t)((b * NHEADS + h) * DKH) * SEQ;

    for (int kb = 0; kb < nkb; ++kb){
        const int kc = kb * 64;
        f32x4 sg[4] = {};
        const u16* kp = kbase + (size_t)(kc + lrow) * QKV_LD + 8 * lkg;
        bf16x8 ka[4], kbv[4];
        #pragma unroll
        for (int g = 0; g < 4; g++){
            const u16* p = kp + (size_t)(16 * g) * QKV_LD;
            ka[g]  = ldb8(p);
            kbv[g] = ldb8(p + 32);
        }
        __builtin_amdgcn_s_setprio(1);
        #pragma unroll
        for (int g = 0; g < 4; g++){
            sg[g] = mfma16(qf0, ka[g],  sg[g]);
            sg[g] = mfma16(qf1, kbv[g], sg[g]);
        }
        __builtin_amdgcn_s_setprio(0);

        #pragma unroll
        for (int e = 0; e < 4; e++){
            const int row = q0 + lkg * 4 + e;
            float v0 = (kc      + lrow > row) ? -1e30f : sg[0][e] * 0.125f;
            float v1 = (kc + 16 + lrow > row) ? -1e30f : sg[1][e] * 0.125f;
            float v2 = (kc + 32 + lrow > row) ? -1e30f : sg[2][e] * 0.125f;
            float v3 = (kc + 48 + lrow > row) ? -1e30f : sg[3][e] * 0.125f;
            float t = fmaxf(fmaxf(v0, v1), fmaxf(v2, v3));
            t = fmaxf(t, __shfl_xor(t, 1));
            t = fmaxf(t, __shfl_xor(t, 2));
            t = fmaxf(t, __shfl_xor(t, 4));
            t = fmaxf(t, __shfl_xor(t, 8));
            const float mn = fmaxf(mr[e], t);
            const float al = __expf(mr[e] - mn);
            const float p0 = __expf(v0 - mn);
            const float p1 = __expf(v1 - mn);
            const float p2 = __expf(v2 - mn);
            const float p3 = __expf(v3 - mn);
            float rsum = (p0 + p1) + (p2 + p3);
            rsum += __shfl_xor(rsum, 1);
            rsum += __shfl_xor(rsum, 2);
            rsum += __shfl_xor(rsum, 4);
            rsum += __shfl_xor(rsum, 8);
            lsum[e] = lsum[e] * al + rsum;
            mr[e] = mn;
            #pragma unroll
            for (int nt = 0; nt < 4; nt++) acc[nt][e] *= al;
            u16* prow = plds[lkg * 4 + e];
            prow[lrow]      = f2bf(p0);
            prow[16 + lrow] = f2bf(p1);
            prow[32 + lrow] = f2bf(p2);
            prow[48 + lrow] = f2bf(p3);
        }
        asm volatile("" ::: "memory"); // keep P writes before the frag read
        const bf16x8 pf0 = ldb8(&plds[lrow][8 * lkg]);
        const bf16x8 pf1 = ldb8(&plds[lrow][32 + 8 * lkg]);
        __builtin_amdgcn_s_setprio(1);
        #pragma unroll
        for (int nt = 0; nt < 4; nt++){
            const u16* vp = vtbase + (size_t)(16 * nt + lrow) * SEQ + kc + 8 * lkg;
            acc[nt] = mfma16(pf0, ldb8(vp),      acc[nt]);
            acc[nt] = mfma16(pf1, ldb8(vp + 32), acc[nt]);
        }
        __builtin_amdgcn_s_setprio(0);
    }
    #pragma unroll
    for (int nt = 0; nt < 4; nt++){
        #pragma unroll
        for (int e = 0; e < 4; e++){
            const int r = q0 + lkg * 4 + e;
            ctx[(size_t)(b * SEQ + r) * D_MODEL + h * DKH + 16 * nt + lrow] =
                f2bf(acc[nt][e] / lsum[e]);
        }
    }
}

// ---------------- launcher ----------------
extern "C" void kernel_launch(void* const* d_in, const int* in_sizes, int n_in,
                              void* d_out, int out_size, void* d_ws, size_t ws_size,
                              hipStream_t stream){
    const int*   ids  = (const int*)  d_in[0];
    const float* tok  = (const float*)d_in[1];
    const float* pe   = (const float*)d_in[2];
    const float* Wq   = (const float*)d_in[3];
    const float* Wk   = (const float*)d_in[4];
    const float* Wv   = (const float*)d_in[5];
    const float* Wo   = (const float*)d_in[6];
    const float* bo   = (const float*)d_in[7];
    const float* W1   = (const float*)d_in[8];
    const float* b1   = (const float*)d_in[9];
    const float* W2   = (const float*)d_in[10];
    const float* b2   = (const float*)d_in[11];
    const float* ln1g = (const float*)d_in[12];
    const float* ln1b = (const float*)d_in[13];
    const float* ln2g = (const float*)d_in[14];
    const float* ln2b = (const float*)d_in[15];
    const float* lnfg = (const float*)d_in[16];
    const float* lnfb = (const float*)d_in[17];
    const float* Wh   = (const float*)d_in[18];
    float* out = (float*)d_out;

    char* ws = (char*)d_ws;
    size_t off = 0;
    auto alloc = [&](size_t bytes) -> void* {
        void* p = ws + off;
        off += (bytes + 255) & ~(size_t)255;
        return p;
    };
    float* x     = (float*)alloc((size_t)NTOK * D_MODEL * 4);   // 8 MB
    u16*   hbuf  = (u16*)  alloc((size_t)NTOK * D_MODEL * 2);   // 4 MB
    u16*   qkv   = (u16*)  alloc((size_t)NTOK * QKV_LD  * 2);   // 12 MB
    u16*   vt    = (u16*)  alloc((size_t)NTOK * D_MODEL * 2);   // 4 MB
    u16*   ctx   = (u16*)  alloc((size_t)NTOK * D_MODEL * 2);   // 4 MB
    u16*   f1    = (u16*)  alloc((size_t)NTOK * DFF     * 2);   // 16 MB
    float* pbuf  = (float*)alloc((size_t)2 * NTOK * D_MODEL * 4); // 16 MB (2 split-K partials)
    u16*   wqkvT = (u16*)  alloc((size_t)QKV_LD * D_MODEL * 2); // 6 MB
    u16*   woT   = (u16*)  alloc((size_t)D_MODEL * D_MODEL * 2);// 2 MB
    u16*   w1T   = (u16*)  alloc((size_t)DFF * D_MODEL * 2);    // 8 MB
    u16*   w2T   = (u16*)  alloc((size_t)D_MODEL * DFF * 2);    // 8 MB
    u16*   whB   = (u16*)  alloc((size_t)NVOCAB * D_MODEL * 2); // 65.5 MB
    (void)ws_size; (void)in_sizes; (void)n_in; (void)out_size;

    k_embed<<<NTOK, 256, 0, stream>>>(ids, tok, pe, x);

    for (int l = 0; l < NLAYERS; l++){
        const size_t wdd = (size_t)l * D_MODEL * D_MODEL;
        const size_t wdf = (size_t)l * D_MODEL * DFF;
        // layer 0: append 16000 Wh-cast blocks to the transpose launch
        const int tgrid = (l == 0) ? (6144 + 16000) : 6144;
        k_tconv_fused<<<tgrid, 256, 0, stream>>>(
            Wq + wdd, Wk + wdd, Wv + wdd, Wo + wdd, W1 + wdf, W2 + wdf,
            wqkvT, woT, w1T, w2T, Wh, whB);

        if (l == 0)
            k_ln<<<NTOK, 256, 0, stream>>>(x, ln1g, ln1b, hbuf);
        else
            k_ln_acc<2><<<NTOK, 256, 0, stream>>>(x, pbuf, b2 + (l - 1) * D_MODEL,
                ln1g + l * D_MODEL, ln1b + l * D_MODEL, hbuf);

        // QKV GEMM (+fused V-transpose): grid 384 = 8 xcd * 3 n * 16 m
        k_gemm128p<false, false, true, false, true><<<384, 256, 0, stream>>>(
            hbuf, wqkvT, nullptr, nullptr, qkv, vt, QKV_LD, D_MODEL, 24, 16, 1);
        k_attn<<<512, 256, 0, stream>>>(qkv, vt, ctx);

        // Wo GEMM split-K=2: grid 256
        k_gemm128p<false, false, false, true, false><<<256, 256, 0, stream>>>(
            ctx, woT, nullptr, pbuf, nullptr, nullptr, D_MODEL, D_MODEL, 8, 16, 2);
        k_ln_acc<2><<<NTOK, 256, 0, stream>>>(x, pbuf, bo + l * D_MODEL,
            ln2g + l * D_MODEL, ln2b + l * D_MODEL, hbuf);

        // W1 GEMM: grid 512 = 8 xcd * 4 n * 16 m
        k_gemm128p<true, true, true, false, false><<<512, 256, 0, stream>>>(
            hbuf, w1T, b1 + l * DFF, nullptr, f1, nullptr, DFF, D_MODEL, 32, 16, 1);
        // W2 GEMM split-K=2: grid 256
        k_gemm128p<false, false, false, true, false><<<256, 256, 0, stream>>>(
            f1, w2T, nullptr, pbuf, nullptr, nullptr, D_MODEL, DFF, 8, 16, 2);
    }

    k_ln_acc<2><<<NTOK, 256, 0, stream>>>(x, pbuf, b2 + 3 * D_MODEL,
        lnfg, lnfb, hbuf);
    // head GEMM: k_gemm_head256 — best measured (176-182 us, FETCH 115MB).
    k_gemm_head256<<<1000, 512, 0, stream>>>(whB, hbuf, out);
}

// Round 19
// 906.886 us; speedup vs baseline: 1.0220x; 1.0006x over previous
//
#include <hip/hip_runtime.h>
#include <stdint.h>

typedef unsigned short u16;
typedef unsigned int   u32;

#define D_MODEL 1024
#define NHEADS  16
#define DKH     64
#define DFF     4096
#define NLAYERS 4
#define BATCH   2
#define SEQ     1024
#define NTOK    (BATCH*SEQ)
#define NVOCAB  32000
#define QKV_LD  3072

typedef __bf16 bf16x8 __attribute__((ext_vector_type(8)));
typedef float  f32x4  __attribute__((ext_vector_type(4)));
typedef u32    u32x4  __attribute__((ext_vector_type(4)));

static __device__ __forceinline__ u16 f2bf(float f){
    union { float f; u32 u; } v; v.f = f;
    return (u16)((v.u + 0x7fffu + ((v.u >> 16) & 1u)) >> 16);
}
static __device__ __forceinline__ u32 pk2(float lo, float hi){
    return (u32)f2bf(lo) | ((u32)f2bf(hi) << 16);
}
static __device__ __forceinline__ bf16x8 ldb8(const u16* p){
    return *reinterpret_cast<const bf16x8*>(p);
}
static __device__ __forceinline__ f32x4 mfma16(bf16x8 a, bf16x8 b, f32x4 c){
    return __builtin_amdgcn_mfma_f32_16x16x32_bf16(a, b, c, 0, 0, 0);
}
static __device__ __forceinline__ void gld16(const void* g, void* l){
    __builtin_amdgcn_global_load_lds((__attribute__((address_space(1))) u32*)g,
                                     (__attribute__((address_space(3))) u32*)l, 16, 0, 0);
}

// ---------------- embedding: x = tok[id]*sqrt(d) + pe[s] ----------------
__global__ __launch_bounds__(256) void k_embed(const int* __restrict__ ids,
        const float* __restrict__ tok, const float* __restrict__ pe,
        float* __restrict__ x){
    int t = blockIdx.x;
    int c = threadIdx.x * 4;
    int id = ids[t];
    int s = t & (SEQ - 1);
    float4 tv = *(const float4*)(tok + (size_t)id * D_MODEL + c);
    float4 pv = *(const float4*)(pe  + (size_t)s  * D_MODEL + c);
    float4 o;
    o.x = tv.x * 32.0f + pv.x;
    o.y = tv.y * 32.0f + pv.y;
    o.z = tv.z * 32.0f + pv.z;
    o.w = tv.w * 32.0f + pv.w;
    *(float4*)(x + (size_t)t * D_MODEL + c) = o;
}

// ---------------- layernorm (f32 in -> bf16 out) ----------------
__global__ __launch_bounds__(256) void k_ln(const float* __restrict__ x,
        const float* __restrict__ g, const float* __restrict__ b,
        u16* __restrict__ out){
    int t = blockIdx.x;
    int tid = threadIdx.x;
    float4 v = *(const float4*)(x + (size_t)t * D_MODEL + tid * 4);
    float s  = v.x + v.y + v.z + v.w;
    float ss = v.x*v.x + v.y*v.y + v.z*v.z + v.w*v.w;
    #pragma unroll
    for (int off = 1; off < 64; off <<= 1){
        s  += __shfl_xor(s, off);
        ss += __shfl_xor(ss, off);
    }
    __shared__ float rs[4], rss[4];
    int w = tid >> 6;
    if ((tid & 63) == 0){ rs[w] = s; rss[w] = ss; }
    __syncthreads();
    s  = rs[0] + rs[1] + rs[2] + rs[3];
    ss = rss[0] + rss[1] + rss[2] + rss[3];
    float mu  = s * (1.0f / D_MODEL);
    float var = ss * (1.0f / D_MODEL) - mu * mu;
    float rstd = rsqrtf(var + 1e-5f);
    float4 gg = *(const float4*)(g + tid * 4);
    float4 bb = *(const float4*)(b + tid * 4);
    uint2 pkv;
    pkv.x = pk2((v.x - mu) * rstd * gg.x + bb.x, (v.y - mu) * rstd * gg.y + bb.y);
    pkv.y = pk2((v.z - mu) * rstd * gg.z + bb.z, (v.w - mu) * rstd * gg.w + bb.w);
    *(uint2*)(out + (size_t)t * D_MODEL + tid * 4) = pkv;
}

// ------- layernorm with fused split-K combine: xn = x + sum(p) + bias -------
template<int NP>
__global__ __launch_bounds__(256) void k_ln_acc(float* __restrict__ x,
        const float* __restrict__ pb,
        const float* __restrict__ bias,
        const float* __restrict__ g, const float* __restrict__ b,
        u16* __restrict__ out){
    int t = blockIdx.x;
    int tid = threadIdx.x;
    size_t idx = (size_t)t * D_MODEL + tid * 4;
    float4 v  = *(const float4*)(x + idx);
    float4 bv = *(const float4*)(bias + tid * 4);
    v.x += bv.x; v.y += bv.y; v.z += bv.z; v.w += bv.w;
    #pragma unroll
    for (int p = 0; p < NP; p++){
        float4 a = *(const float4*)(pb + (size_t)p * NTOK * D_MODEL + idx);
        v.x += a.x; v.y += a.y; v.z += a.z; v.w += a.w;
    }
    *(float4*)(x + idx) = v;
    float s  = v.x + v.y + v.z + v.w;
    float ss = v.x*v.x + v.y*v.y + v.z*v.z + v.w*v.w;
    #pragma unroll
    for (int off = 1; off < 64; off <<= 1){
        s  += __shfl_xor(s, off);
        ss += __shfl_xor(ss, off);
    }
    __shared__ float rs[4], rss[4];
    int w = tid >> 6;
    if ((tid & 63) == 0){ rs[w] = s; rss[w] = ss; }
    __syncthreads();
    s  = rs[0] + rs[1] + rs[2] + rs[3];
    ss = rss[0] + rss[1] + rss[2] + rss[3];
    float mu  = s * (1.0f / D_MODEL);
    float var = ss * (1.0f / D_MODEL) - mu * mu;
    float rstd = rsqrtf(var + 1e-5f);
    float4 gg = *(const float4*)(g + tid * 4);
    float4 bb = *(const float4*)(b + tid * 4);
    uint2 pkv;
    pkv.x = pk2((v.x - mu) * rstd * gg.x + bb.x, (v.y - mu) * rstd * gg.y + bb.y);
    pkv.y = pk2((v.z - mu) * rstd * gg.z + bb.z, (v.w - mu) * rstd * gg.w + bb.w);
    *(uint2*)(out + idx) = pkv;
}

// ------------- fused weight transpose+convert (vectorized) + optional cast ---
__global__ __launch_bounds__(256) void k_tconv_fused(
        const float* __restrict__ Wq, const float* __restrict__ Wk,
        const float* __restrict__ Wv, const float* __restrict__ Wo,
        const float* __restrict__ W1, const float* __restrict__ W2,
        u16* __restrict__ wqkvT, u16* __restrict__ woT,
        u16* __restrict__ w1T,   u16* __restrict__ w2T,
        const float* __restrict__ WhS, u16* __restrict__ whD){
    const int id  = blockIdx.x;
    const int tid = threadIdx.x;
    if (id >= 6144){
        size_t i = ((size_t)(id - 6144) * 256 + tid) * 8;
        float4 a = *(const float4*)(WhS + i);
        float4 b = *(const float4*)(WhS + i + 4);
        u32x4 o;
        o.x = pk2(a.x, a.y); o.y = pk2(a.z, a.w);
        o.z = pk2(b.x, b.y); o.w = pk2(b.z, b.w);
        *(u32x4*)(whD + i) = o;
        return;
    }
    __shared__ float tile[32][65];
    const float* in; u16* outp; int Rr, Cc, bx, by;
    if (id < 2048){
        int wsel = id >> 9, t = id & 511;
        bx = t & 15; by = t >> 4; Rr = 1024; Cc = 1024;
        in   = (wsel == 0) ? Wq : (wsel == 1) ? Wk : (wsel == 2) ? Wv : Wo;
        outp = (wsel < 3) ? wqkvT + wsel * 1024 * 1024 : woT;
    } else if (id < 4096){
        int t = id - 2048; bx = t & 63; by = t >> 6; Rr = 1024; Cc = 4096;
        in = W1; outp = w1T;
    } else {
        int t = id - 4096; bx = t & 15; by = t >> 4; Rr = 4096; Cc = 1024;
        in = W2; outp = w2T;
    }
    const int rt = tid >> 4, cq = tid & 15;
    #pragma unroll
    for (int i = 0; i < 2; i++){
        int row = by * 32 + rt + i * 16;
        float4 v = *(const float4*)(in + (size_t)row * Cc + bx * 64 + cq * 4);
        tile[rt + i * 16][cq * 4 + 0] = v.x;
        tile[rt + i * 16][cq * 4 + 1] = v.y;
        tile[rt + i * 16][cq * 4 + 2] = v.z;
        tile[rt + i * 16][cq * 4 + 3] = v.w;
    }
    __syncthreads();
    const int cW = tid >> 3, rg = tid & 7;
    #pragma unroll
    for (int i = 0; i < 2; i++){
        int c = bx * 64 + cW + i * 32;
        float a0 = tile[rg * 4 + 0][cW + i * 32];
        float a1 = tile[rg * 4 + 1][cW + i * 32];
        float a2 = tile[rg * 4 + 2][cW + i * 32];
        float a3 = tile[rg * 4 + 3][cW + i * 32];
        uint2 pv;
        pv.x = pk2(a0, a1);
        pv.y = pk2(a2, a3);
        *(uint2*)(outp + (size_t)c * Rr + by * 32 + rg * 4) = pv;
    }
}

// ---------------- 128-tile deep-pipelined GEMM (layer GEMMs) ----------------
// counted vmcnt(8), raw barriers, both-sides XOR swizzle, setprio.
// VFUSE (QKV only): V-column blocks write transposed into vt (A/B: -4.3 us).
template<bool BIAS, bool RELU, bool OBF16, bool AXISM, bool VFUSE>
__global__ __launch_bounds__(256, 2) void k_gemm128p(
    const u16* __restrict__ A, const u16* __restrict__ Bt,
    const float* __restrict__ bias,
    float* __restrict__ outF, u16* __restrict__ outH, u16* __restrict__ vtOut,
    int N, int Kfull, int NXT, int NMT, int NZ)
{
    __shared__ __align__(16) u16 lds[32768];  // 2 slots x (A 8K + B 8K) elems
    const int bid = blockIdx.x;
    const int xcd = bid & 7;
    const int r   = bid >> 3;
    int m_t, n_t, z;
    if constexpr (AXISM) {
        const int mper = NMT >> 3;
        n_t = r % NXT;
        int r2 = r / NXT;
        z = r2 % NZ;
        m_t = xcd * mper + r2 / NZ;
    } else {
        const int nper = NXT >> 3;
        n_t = xcd * nper + r % nper;
        int r2 = r / nper;
        m_t = r2 % NMT;
        z = r2 / NMT;
    }
    const int m0 = m_t * 128;
    const int n0 = n_t * 128;
    const int Kz = Kfull / NZ;
    const int kbeg = z * Kz;
    const int NT = Kz >> 6;

    const int tid  = threadIdx.x;
    const int w    = tid >> 6;
    const int lane = tid & 63;
    const int wr   = w >> 1, wc = w & 1;            // 2m x 2n wave grid
    const int lrow = lane & 15, lkg = lane >> 4;

    // --- staging addressing ---
    const int srow = tid >> 3;                       // 0..31 row within chunk
    const int ssw  = ((tid & 7) ^ (srow & 7)) * 8;   // pre-swizzled 16B slot
    const u16* aSrc0 = A  + (size_t)(m0 +  0 + srow) * Kfull + kbeg + ssw;
    const u16* aSrc1 = A  + (size_t)(m0 + 32 + srow) * Kfull + kbeg + ssw;
    const u16* aSrc2 = A  + (size_t)(m0 + 64 + srow) * Kfull + kbeg + ssw;
    const u16* aSrc3 = A  + (size_t)(m0 + 96 + srow) * Kfull + kbeg + ssw;
    const u16* bSrc0 = Bt + (size_t)(n0 +  0 + srow) * Kfull + kbeg + ssw;
    const u16* bSrc1 = Bt + (size_t)(n0 + 32 + srow) * Kfull + kbeg + ssw;
    const u16* bSrc2 = Bt + (size_t)(n0 + 64 + srow) * Kfull + kbeg + ssw;
    const u16* bSrc3 = Bt + (size_t)(n0 + 96 + srow) * Kfull + kbeg + ssw;

    // --- frag-read addressing ---
    const int sw0 = ((0 + lkg) ^ (lrow & 7)) * 8;
    const int sw1 = ((4 + lkg) ^ (lrow & 7)) * 8;
    const int aBase = (wr * 64 + lrow) * 64;
    const int bBase = (wc * 64 + lrow) * 64 + 8192;

    f32x4 acc[4][4] = {};

    #define STAGE(s, st) do { \
        u16* ab_ = lds + (s) * 16384 + w * 512; \
        const int ko_ = (st) * 64; \
        gld16(aSrc0 + ko_, ab_);              \
        gld16(aSrc1 + ko_, ab_ + 2048);       \
        gld16(aSrc2 + ko_, ab_ + 4096);       \
        gld16(aSrc3 + ko_, ab_ + 6144);       \
        gld16(bSrc0 + ko_, ab_ + 8192);       \
        gld16(bSrc1 + ko_, ab_ + 10240);      \
        gld16(bSrc2 + ko_, ab_ + 12288);      \
        gld16(bSrc3 + ko_, ab_ + 14336);      \
    } while (0)

    STAGE(0, 0);
    STAGE(1, 1);
    asm volatile("s_waitcnt vmcnt(8)" ::: "memory");
    __builtin_amdgcn_s_barrier();
    __builtin_amdgcn_sched_barrier(0);

    for (int t = 0; t < NT; ++t){
        const int s = t & 1;
        const u16* As = lds + s * 16384;

        bf16x8 af0[4], bf0[4];
        #pragma unroll
        for (int i = 0; i < 4; i++) af0[i] = ldb8(As + aBase + i * 1024 + sw0);
        #pragma unroll
        for (int j = 0; j < 4; j++) bf0[j] = ldb8(As + bBase + j * 1024 + sw0);
        __builtin_amdgcn_s_setprio(1);
        #pragma unroll
        for (int i = 0; i < 4; i++)
            #pragma unroll
            for (int j = 0; j < 4; j++)
                acc[i][j] = mfma16(af0[i], bf0[j], acc[i][j]);
        __builtin_amdgcn_s_setprio(0);

        bf16x8 af1[4], bf1[4];
        #pragma unroll
        for (int i = 0; i < 4; i++) af1[i] = ldb8(As + aBase + i * 1024 + sw1);
        #pragma unroll
        for (int j = 0; j < 4; j++) bf1[j] = ldb8(As + bBase + j * 1024 + sw1);
        asm volatile("s_waitcnt lgkmcnt(0)" ::: "memory");
        __builtin_amdgcn_sched_barrier(0);
        __builtin_amdgcn_s_barrier();          // all waves done reading slot s
        __builtin_amdgcn_sched_barrier(0);

        STAGE(s, (t + 2 < NT) ? t + 2 : NT - 1);

        __builtin_amdgcn_s_setprio(1);
        #pragma unroll
        for (int i = 0; i < 4; i++)
            #pragma unroll
            for (int j = 0; j < 4; j++)
                acc[i][j] = mfma16(af1[i], bf1[j], acc[i][j]);
        __builtin_amdgcn_s_setprio(0);

        asm volatile("s_waitcnt vmcnt(8)" ::: "memory");
        __builtin_amdgcn_s_barrier();          // slot s^1 (t+1) now ready
        __builtin_amdgcn_sched_barrier(0);
    }
    #undef STAGE

    float* outFz = outF;
    if (NZ > 1) outFz += (size_t)z * (NMT * 128) * N;

    #pragma unroll
    for (int i = 0; i < 4; i++){
        #pragma unroll
        for (int j = 0; j < 4; j++){
            const int c = n0 + 64 * wc + 16 * j + lrow;
            if (VFUSE && n0 >= 2048) {
                const int hv = (c - 2048) >> 6, dh = (c - 2048) & 63;
                const int r0 = m0 + 64 * wr + 16 * i + lkg * 4;
                const int bb = r0 >> 10, ss = r0 & 1023;
                uint2 pv;
                pv.x = pk2(acc[i][j][0], acc[i][j][1]);
                pv.y = pk2(acc[i][j][2], acc[i][j][3]);
                *(uint2*)(vtOut + (((size_t)((bb * 16 + hv) * 64 + dh)) << 10) + ss) = pv;
            } else {
                float bv = 0.0f;
                if constexpr (BIAS) bv = bias[c];
                #pragma unroll
                for (int e = 0; e < 4; e++){
                    const int rr = m0 + 64 * wr + 16 * i + lkg * 4 + e;
                    float vv = acc[i][j][e] + bv;
                    if constexpr (RELU) vv = fmaxf(vv, 0.0f);
                    const size_t idx = (size_t)rr * N + c;
                    if constexpr (OBF16) outH[idx] = f2bf(vv);
                    else                 outFz[idx] = vv;
                }
            }
        }
    }
}

// ---------------- head GEMM: 256x256 tile, 512 thr, BK=64, deep pipeline ----
__global__ __launch_bounds__(512, 2) void k_gemm_head256(
    const u16* __restrict__ A, const u16* __restrict__ Bt,
    float* __restrict__ out)
{
    __shared__ __align__(16) u16 lds[65536];
    const int bid = blockIdx.x;
    const int swz = (bid & 7) * 125 + (bid >> 3);   // XCD-chunked, 1000%8==0
    const int m0 = (swz >> 3) * 256;                // vocab tile
    const int n0 = (swz & 7) * 256;                 // token tile

    const int tid  = threadIdx.x;
    const int w    = tid >> 6;
    const int lane = tid & 63;
    const int wr   = w >> 2, wc = w & 3;            // 2m x 4n wave grid
    const int lrow = lane & 15, lkg = lane >> 4;

    const int srow = tid >> 3;
    const int ssw  = ((tid & 7) ^ (srow & 7)) * 8;
    const u16* aSrc0 = A  + (size_t)(m0 +   0 + srow) * D_MODEL + ssw;
    const u16* aSrc1 = A  + (size_t)(m0 +  64 + srow) * D_MODEL + ssw;
    const u16* aSrc2 = A  + (size_t)(m0 + 128 + srow) * D_MODEL + ssw;
    const u16* aSrc3 = A  + (size_t)(m0 + 192 + srow) * D_MODEL + ssw;
    const u16* bSrc0 = Bt + (size_t)(n0 +   0 + srow) * D_MODEL + ssw;
    const u16* bSrc1 = Bt + (size_t)(n0 +  64 + srow) * D_MODEL + ssw;
    const u16* bSrc2 = Bt + (size_t)(n0 + 128 + srow) * D_MODEL + ssw;
    const u16* bSrc3 = Bt + (size_t)(n0 + 192 + srow) * D_MODEL + ssw;

    const int sw0 = ((0 + lkg) ^ (lrow & 7)) * 8;
    const int sw1 = ((4 + lkg) ^ (lrow & 7)) * 8;
    const int aBase = (wr * 128 + lrow) * 64;
    const int bBase = (wc * 64  + lrow) * 64;

    f32x4 acc[8][4] = {};

    #define STAGE(s, st) do { \
        u16* ab_ = lds + (s) * 32768 + w * 512; \
        const int ko_ = (st) * 64; \
        gld16(aSrc0 + ko_, ab_);              \
        gld16(aSrc1 + ko_, ab_ + 4096);       \
        gld16(aSrc2 + ko_, ab_ + 8192);       \
        gld16(aSrc3 + ko_, ab_ + 12288);      \
        gld16(bSrc0 + ko_, ab_ + 16384);      \
        gld16(bSrc1 + ko_, ab_ + 20480);      \
        gld16(bSrc2 + ko_, ab_ + 24576);      \
        gld16(bSrc3 + ko_, ab_ + 28672);      \
    } while (0)

    STAGE(0, 0);
    STAGE(1, 1);
    asm volatile("s_waitcnt vmcnt(8)" ::: "memory");
    __builtin_amdgcn_s_barrier();
    __builtin_amdgcn_sched_barrier(0);

    const int NT = D_MODEL / 64;   // 16
    for (int t = 0; t < NT; ++t){
        const int s = t & 1;
        const u16* As = lds + s * 32768;
        const u16* Bs = As + 16384;

        bf16x8 af0[8], bf0[4];
        #pragma unroll
        for (int i = 0; i < 8; i++) af0[i] = ldb8(As + aBase + i * 1024 + sw0);
        #pragma unroll
        for (int j = 0; j < 4; j++) bf0[j] = ldb8(Bs + bBase + j * 1024 + sw0);
        __builtin_amdgcn_s_setprio(1);
        #pragma unroll
        for (int i = 0; i < 8; i++)
            #pragma unroll
            for (int j = 0; j < 4; j++)
                acc[i][j] = mfma16(af0[i], bf0[j], acc[i][j]);
        __builtin_amdgcn_s_setprio(0);

        bf16x8 af1[8], bf1[4];
        #pragma unroll
        for (int i = 0; i < 8; i++) af1[i] = ldb8(As + aBase + i * 1024 + sw1);
        #pragma unroll
        for (int j = 0; j < 4; j++) bf1[j] = ldb8(Bs + bBase + j * 1024 + sw1);
        asm volatile("s_waitcnt lgkmcnt(0)" ::: "memory");
        __builtin_amdgcn_sched_barrier(0);
        __builtin_amdgcn_s_barrier();
        __builtin_amdgcn_sched_barrier(0);

        STAGE(s, (t + 2 < NT) ? t + 2 : NT - 1);

        __builtin_amdgcn_s_setprio(1);
        #pragma unroll
        for (int i = 0; i < 8; i++)
            #pragma unroll
            for (int j = 0; j < 4; j++)
                acc[i][j] = mfma16(af1[i], bf1[j], acc[i][j]);
        __builtin_amdgcn_s_setprio(0);

        asm volatile("s_waitcnt vmcnt(8)" ::: "memory");
        __builtin_amdgcn_s_barrier();
        __builtin_amdgcn_sched_barrier(0);
    }
    #undef STAGE

    #pragma unroll
    for (int i = 0; i < 8; i++){
        const int m = m0 + wr * 128 + i * 16 + lkg * 4;
        #pragma unroll
        for (int j = 0; j < 4; j++){
            const int n = n0 + wc * 64 + j * 16 + lrow;
            float4 st;
            st.x = acc[i][j][0]; st.y = acc[i][j][1];
            st.z = acc[i][j][2]; st.w = acc[i][j][3];
            *(float4*)(out + (size_t)n * NVOCAB + m) = st;
        }
    }
}

// ---- flash attention: 1 wave / 16 q-rows, KVBLK=64, SWAPPED QK^T softmax ---
// S = mfma(K, Q): lane holds 16 scores for ONE q-row (col = lane&15).
// Row-reduce = in-lane max/sum + 2 shfl_xor (16,32); acc-rescale via 4
// ds_bpermute broadcasts. 8 cross-lane ops/block vs 32 in the unswapped form.
// P lands in plds[q][key] — exactly the PV A-fragment layout (PV unchanged).
__global__ __launch_bounds__(256) void k_attn(const u16* __restrict__ qkv,
        const u16* __restrict__ vt, u16* __restrict__ ctx){
    const int wid  = (blockIdx.x << 2) + (threadIdx.x >> 6);
    const int lane = threadIdx.x & 63;
    const int qt = wid & 63;
    const int h  = (wid >> 6) & 15;
    const int b  = wid >> 10;
    const int q0 = qt * 16;
    const int lo = lane & 15, hi = lane >> 4;

    __shared__ __align__(16) u16 plds_all[4][16][72]; // 144B rows, <=2-way banks
    u16 (*plds)[72] = plds_all[threadIdx.x >> 6];

    const u16* qbase = qkv + (size_t)(b * SEQ + q0 + lo) * QKV_LD + h * DKH + 8 * hi;
    const bf16x8 qf0 = ldb8(qbase);
    const bf16x8 qf1 = ldb8(qbase + 32);

    const int qrow = q0 + lo;        // this lane's softmax-owner row
    float mr = -1e30f, lsum = 0.0f;  // scalar state for q-row `lo`
    f32x4 acc[4] = {};

    const int nkb = (q0 >> 6) + 1;
    const u16* kbase  = qkv + (size_t)(b * SEQ) * QKV_LD + 1024 + h * DKH;
    const u16* vtbase = vt + (size_t)((b * NHEADS + h) * DKH) * SEQ;

    for (int kb = 0; kb < nkb; ++kb){
        const int kc = kb * 64;
        f32x4 sg[4] = {};
        const u16* kp = kbase + (size_t)(kc + lo) * QKV_LD + 8 * hi;
        bf16x8 ka[4], kbv[4];
        #pragma unroll
        for (int g = 0; g < 4; g++){
            const u16* p = kp + (size_t)(16 * g) * QKV_LD;
            ka[g]  = ldb8(p);
            kbv[g] = ldb8(p + 32);
        }
        __builtin_amdgcn_s_setprio(1);
        #pragma unroll
        for (int g = 0; g < 4; g++){
            sg[g] = mfma16(ka[g],  qf0, sg[g]);   // SWAPPED: S[key][q]
            sg[g] = mfma16(kbv[g], qf1, sg[g]);
        }
        __builtin_amdgcn_s_setprio(0);

        // mask + in-lane max over this lane's 16 scores (all for q-row `lo`)
        float pm = -1e30f;
        #pragma unroll
        for (int g = 0; g < 4; g++){
            #pragma unroll
            for (int e = 0; e < 4; e++){
                const int key = kc + 16 * g + hi * 4 + e;
                float v = (key > qrow) ? -1e30f : sg[g][e] * 0.125f;
                sg[g][e] = v;
                pm = fmaxf(pm, v);
            }
        }
        pm = fmaxf(pm, __shfl_xor(pm, 16));
        pm = fmaxf(pm, __shfl_xor(pm, 32));
        const float mn = fmaxf(mr, pm);
        const float al = __expf(mr - mn);
        mr = mn;

        float rsum = 0.0f;
        u16* prow = plds[lo];
        #pragma unroll
        for (int g = 0; g < 4; g++){
            #pragma unroll
            for (int e = 0; e < 4; e++){
                float p = __expf(sg[g][e] - mn);
                rsum += p;
                prow[16 * g + hi * 4 + e] = f2bf(p);
            }
        }
        rsum += __shfl_xor(rsum, 16);
        rsum += __shfl_xor(rsum, 32);
        lsum = lsum * al + rsum;

        // rescale acc: acc[nt][e] holds O[q-row = hi*4+e]; owner lane = hi*4+e
        #pragma unroll
        for (int e = 0; e < 4; e++){
            const float ale = __shfl(al, hi * 4 + e);
            #pragma unroll
            for (int nt = 0; nt < 4; nt++) acc[nt][e] *= ale;
        }

        asm volatile("" ::: "memory"); // keep P writes before the frag read
        const bf16x8 pf0 = ldb8(&plds[lo][8 * hi]);
        const bf16x8 pf1 = ldb8(&plds[lo][32 + 8 * hi]);
        __builtin_amdgcn_s_setprio(1);
        #pragma unroll
        for (int nt = 0; nt < 4; nt++){
            const u16* vp = vtbase + (size_t)(16 * nt + lo) * SEQ + kc + 8 * hi;
            acc[nt] = mfma16(pf0, ldb8(vp),      acc[nt]);
            acc[nt] = mfma16(pf1, ldb8(vp + 32), acc[nt]);
        }
        __builtin_amdgcn_s_setprio(0);
    }
    #pragma unroll
    for (int e = 0; e < 4; e++){
        const float inv = 1.0f / __shfl(lsum, hi * 4 + e);
        const int r = q0 + hi * 4 + e;
        #pragma unroll
        for (int nt = 0; nt < 4; nt++){
            ctx[(size_t)(b * SEQ + r) * D_MODEL + h * DKH + 16 * nt + lo] =
                f2bf(acc[nt][e] * inv);
        }
    }
}

// ---------------- launcher ----------------
extern "C" void kernel_launch(void* const* d_in, const int* in_sizes, int n_in,
                              void* d_out, int out_size, void* d_ws, size_t ws_size,
                              hipStream_t stream){
    const int*   ids  = (const int*)  d_in[0];
    const float* tok  = (const float*)d_in[1];
    const float* pe   = (const float*)d_in[2];
    const float* Wq   = (const float*)d_in[3];
    const float* Wk   = (const float*)d_in[4];
    const float* Wv   = (const float*)d_in[5];
    const float* Wo   = (const float*)d_in[6];
    const float* bo   = (const float*)d_in[7];
    const float* W1   = (const float*)d_in[8];
    const float* b1   = (const float*)d_in[9];
    const float* W2   = (const float*)d_in[10];
    const float* b2   = (const float*)d_in[11];
    const float* ln1g = (const float*)d_in[12];
    const float* ln1b = (const float*)d_in[13];
    const float* ln2g = (const float*)d_in[14];
    const float* ln2b = (const float*)d_in[15];
    const float* lnfg = (const float*)d_in[16];
    const float* lnfb = (const float*)d_in[17];
    const float* Wh   = (const float*)d_in[18];
    float* out = (float*)d_out;

    char* ws = (char*)d_ws;
    size_t off = 0;
    auto alloc = [&](size_t bytes) -> void* {
        void* p = ws + off;
        off += (bytes + 255) & ~(size_t)255;
        return p;
    };
    float* x     = (float*)alloc((size_t)NTOK * D_MODEL * 4);   // 8 MB
    u16*   hbuf  = (u16*)  alloc((size_t)NTOK * D_MODEL * 2);   // 4 MB
    u16*   qkv   = (u16*)  alloc((size_t)NTOK * QKV_LD  * 2);   // 12 MB
    u16*   vt    = (u16*)  alloc((size_t)NTOK * D_MODEL * 2);   // 4 MB
    u16*   ctx   = (u16*)  alloc((size_t)NTOK * D_MODEL * 2);   // 4 MB
    u16*   f1    = (u16*)  alloc((size_t)NTOK * DFF     * 2);   // 16 MB
    float* pbuf  = (float*)alloc((size_t)2 * NTOK * D_MODEL * 4); // 16 MB
    u16*   wqkvT = (u16*)  alloc((size_t)QKV_LD * D_MODEL * 2); // 6 MB
    u16*   woT   = (u16*)  alloc((size_t)D_MODEL * D_MODEL * 2);// 2 MB
    u16*   w1T   = (u16*)  alloc((size_t)DFF * D_MODEL * 2);    // 8 MB
    u16*   w2T   = (u16*)  alloc((size_t)D_MODEL * DFF * 2);    // 8 MB
    u16*   whB   = (u16*)  alloc((size_t)NVOCAB * D_MODEL * 2); // 65.5 MB
    (void)ws_size; (void)in_sizes; (void)n_in; (void)out_size;

    k_embed<<<NTOK, 256, 0, stream>>>(ids, tok, pe, x);

    for (int l = 0; l < NLAYERS; l++){
        const size_t wdd = (size_t)l * D_MODEL * D_MODEL;
        const size_t wdf = (size_t)l * D_MODEL * DFF;
        const int tgrid = (l == 0) ? (6144 + 16000) : 6144;
        k_tconv_fused<<<tgrid, 256, 0, stream>>>(
            Wq + wdd, Wk + wdd, Wv + wdd, Wo + wdd, W1 + wdf, W2 + wdf,
            wqkvT, woT, w1T, w2T, Wh, whB);

        if (l == 0)
            k_ln<<<NTOK, 256, 0, stream>>>(x, ln1g, ln1b, hbuf);
        else
            k_ln_acc<2><<<NTOK, 256, 0, stream>>>(x, pbuf, b2 + (l - 1) * D_MODEL,
                ln1g + l * D_MODEL, ln1b + l * D_MODEL, hbuf);

        // QKV GEMM (+fused V-transpose): grid 384 = 8 xcd * 3 n * 16 m
        k_gemm128p<false, false, true, false, true><<<384, 256, 0, stream>>>(
            hbuf, wqkvT, nullptr, nullptr, qkv, vt, QKV_LD, D_MODEL, 24, 16, 1);
        k_attn<<<512, 256, 0, stream>>>(qkv, vt, ctx);

        // Wo GEMM split-K=2: grid 256
        k_gemm128p<false, false, false, true, false><<<256, 256, 0, stream>>>(
            ctx, woT, nullptr, pbuf, nullptr, nullptr, D_MODEL, D_MODEL, 8, 16, 2);
        k_ln_acc<2><<<NTOK, 256, 0, stream>>>(x, pbuf, bo + l * D_MODEL,
            ln2g + l * D_MODEL, ln2b + l * D_MODEL, hbuf);

        // W1 GEMM: grid 512 = 8 xcd * 4 n * 16 m
        k_gemm128p<true, true, true, false, false><<<512, 256, 0, stream>>>(
            hbuf, w1T, b1 + l * DFF, nullptr, f1, nullptr, DFF, D_MODEL, 32, 16, 1);
        // W2 GEMM split-K=2: grid 256
        k_gemm128p<false, false, false, true, false><<<256, 256, 0, stream>>>(
            f1, w2T, nullptr, pbuf, nullptr, nullptr, D_MODEL, DFF, 8, 16, 2);
    }

    k_ln_acc<2><<<NTOK, 256, 0, stream>>>(x, pbuf, b2 + 3 * D_MODEL,
        lnfg, lnfb, hbuf);
    // head GEMM: k_gemm_head256 — best measured (176-182 us, FETCH 115MB).
    k_gemm_head256<<<1000, 512, 0, stream>>>(whB, hbuf, out);
}

// Round 20
// 900.383 us; speedup vs baseline: 1.0294x; 1.0072x over previous
//
#include <hip/hip_runtime.h>
#include <stdint.h>

typedef unsigned short u16;
typedef unsigned int   u32;

#define D_MODEL 1024
#define NHEADS  16
#define DKH     64
#define DFF     4096
#define NLAYERS 4
#define BATCH   2
#define SEQ     1024
#define NTOK    (BATCH*SEQ)
#define NVOCAB  32000
#define QKV_LD  3072

typedef __bf16 bf16x8 __attribute__((ext_vector_type(8)));
typedef float  f32x4  __attribute__((ext_vector_type(4)));
typedef u32    u32x4  __attribute__((ext_vector_type(4)));

static __device__ __forceinline__ u16 f2bf(float f){
    union { float f; u32 u; } v; v.f = f;
    return (u16)((v.u + 0x7fffu + ((v.u >> 16) & 1u)) >> 16);
}
static __device__ __forceinline__ u32 pk2(float lo, float hi){
    return (u32)f2bf(lo) | ((u32)f2bf(hi) << 16);
}
static __device__ __forceinline__ bf16x8 ldb8(const u16* p){
    return *reinterpret_cast<const bf16x8*>(p);
}
static __device__ __forceinline__ f32x4 mfma16(bf16x8 a, bf16x8 b, f32x4 c){
    return __builtin_amdgcn_mfma_f32_16x16x32_bf16(a, b, c, 0, 0, 0);
}
static __device__ __forceinline__ void gld16(const void* g, void* l){
    __builtin_amdgcn_global_load_lds((__attribute__((address_space(1))) u32*)g,
                                     (__attribute__((address_space(3))) u32*)l, 16, 0, 0);
}

// ---------------- embedding: x = tok[id]*sqrt(d) + pe[s] ----------------
__global__ __launch_bounds__(256) void k_embed(const int* __restrict__ ids,
        const float* __restrict__ tok, const float* __restrict__ pe,
        float* __restrict__ x){
    int t = blockIdx.x;
    int c = threadIdx.x * 4;
    int id = ids[t];
    int s = t & (SEQ - 1);
    float4 tv = *(const float4*)(tok + (size_t)id * D_MODEL + c);
    float4 pv = *(const float4*)(pe  + (size_t)s  * D_MODEL + c);
    float4 o;
    o.x = tv.x * 32.0f + pv.x;
    o.y = tv.y * 32.0f + pv.y;
    o.z = tv.z * 32.0f + pv.z;
    o.w = tv.w * 32.0f + pv.w;
    *(float4*)(x + (size_t)t * D_MODEL + c) = o;
}

// ---------------- layernorm (f32 in -> bf16 out) ----------------
__global__ __launch_bounds__(256) void k_ln(const float* __restrict__ x,
        const float* __restrict__ g, const float* __restrict__ b,
        u16* __restrict__ out){
    int t = blockIdx.x;
    int tid = threadIdx.x;
    float4 v = *(const float4*)(x + (size_t)t * D_MODEL + tid * 4);
    float s  = v.x + v.y + v.z + v.w;
    float ss = v.x*v.x + v.y*v.y + v.z*v.z + v.w*v.w;
    #pragma unroll
    for (int off = 1; off < 64; off <<= 1){
        s  += __shfl_xor(s, off);
        ss += __shfl_xor(ss, off);
    }
    __shared__ float rs[4], rss[4];
    int w = tid >> 6;
    if ((tid & 63) == 0){ rs[w] = s; rss[w] = ss; }
    __syncthreads();
    s  = rs[0] + rs[1] + rs[2] + rs[3];
    ss = rss[0] + rss[1] + rss[2] + rss[3];
    float mu  = s * (1.0f / D_MODEL);
    float var = ss * (1.0f / D_MODEL) - mu * mu;
    float rstd = rsqrtf(var + 1e-5f);
    float4 gg = *(const float4*)(g + tid * 4);
    float4 bb = *(const float4*)(b + tid * 4);
    uint2 pkv;
    pkv.x = pk2((v.x - mu) * rstd * gg.x + bb.x, (v.y - mu) * rstd * gg.y + bb.y);
    pkv.y = pk2((v.z - mu) * rstd * gg.z + bb.z, (v.w - mu) * rstd * gg.w + bb.w);
    *(uint2*)(out + (size_t)t * D_MODEL + tid * 4) = pkv;
}

// ------- layernorm with fused split-K combine: xn = x + sum(p) + bias -------
template<int NP>
__global__ __launch_bounds__(256) void k_ln_acc(float* __restrict__ x,
        const float* __restrict__ pb,
        const float* __restrict__ bias,
        const float* __restrict__ g, const float* __restrict__ b,
        u16* __restrict__ out){
    int t = blockIdx.x;
    int tid = threadIdx.x;
    size_t idx = (size_t)t * D_MODEL + tid * 4;
    float4 v  = *(const float4*)(x + idx);
    float4 bv = *(const float4*)(bias + tid * 4);
    v.x += bv.x; v.y += bv.y; v.z += bv.z; v.w += bv.w;
    #pragma unroll
    for (int p = 0; p < NP; p++){
        float4 a = *(const float4*)(pb + (size_t)p * NTOK * D_MODEL + idx);
        v.x += a.x; v.y += a.y; v.z += a.z; v.w += a.w;
    }
    *(float4*)(x + idx) = v;
    float s  = v.x + v.y + v.z + v.w;
    float ss = v.x*v.x + v.y*v.y + v.z*v.z + v.w*v.w;
    #pragma unroll
    for (int off = 1; off < 64; off <<= 1){
        s  += __shfl_xor(s, off);
        ss += __shfl_xor(ss, off);
    }
    __shared__ float rs[4], rss[4];
    int w = tid >> 6;
    if ((tid & 63) == 0){ rs[w] = s; rss[w] = ss; }
    __syncthreads();
    s  = rs[0] + rs[1] + rs[2] + rs[3];
    ss = rss[0] + rss[1] + rss[2] + rss[3];
    float mu  = s * (1.0f / D_MODEL);
    float var = ss * (1.0f / D_MODEL) - mu * mu;
    float rstd = rsqrtf(var + 1e-5f);
    float4 gg = *(const float4*)(g + tid * 4);
    float4 bb = *(const float4*)(b + tid * 4);
    uint2 pkv;
    pkv.x = pk2((v.x - mu) * rstd * gg.x + bb.x, (v.y - mu) * rstd * gg.y + bb.y);
    pkv.y = pk2((v.z - mu) * rstd * gg.z + bb.z, (v.w - mu) * rstd * gg.w + bb.w);
    *(uint2*)(out + idx) = pkv;
}

// ------------- fused weight transpose+convert (vectorized) + optional cast ---
__global__ __launch_bounds__(256) void k_tconv_fused(
        const float* __restrict__ Wq, const float* __restrict__ Wk,
        const float* __restrict__ Wv, const float* __restrict__ Wo,
        const float* __restrict__ W1, const float* __restrict__ W2,
        u16* __restrict__ wqkvT, u16* __restrict__ woT,
        u16* __restrict__ w1T,   u16* __restrict__ w2T,
        const float* __restrict__ WhS, u16* __restrict__ whD){
    const int id  = blockIdx.x;
    const int tid = threadIdx.x;
    if (id >= 6144){
        size_t i = ((size_t)(id - 6144) * 256 + tid) * 8;
        float4 a = *(const float4*)(WhS + i);
        float4 b = *(const float4*)(WhS + i + 4);
        u32x4 o;
        o.x = pk2(a.x, a.y); o.y = pk2(a.z, a.w);
        o.z = pk2(b.x, b.y); o.w = pk2(b.z, b.w);
        *(u32x4*)(whD + i) = o;
        return;
    }
    __shared__ float tile[32][65];
    const float* in; u16* outp; int Rr, Cc, bx, by;
    if (id < 2048){
        int wsel = id >> 9, t = id & 511;
        bx = t & 15; by = t >> 4; Rr = 1024; Cc = 1024;
        in   = (wsel == 0) ? Wq : (wsel == 1) ? Wk : (wsel == 2) ? Wv : Wo;
        outp = (wsel < 3) ? wqkvT + wsel * 1024 * 1024 : woT;
    } else if (id < 4096){
        int t = id - 2048; bx = t & 63; by = t >> 6; Rr = 1024; Cc = 4096;
        in = W1; outp = w1T;
    } else {
        int t = id - 4096; bx = t & 15; by = t >> 4; Rr = 4096; Cc = 1024;
        in = W2; outp = w2T;
    }
    const int rt = tid >> 4, cq = tid & 15;
    #pragma unroll
    for (int i = 0; i < 2; i++){
        int row = by * 32 + rt + i * 16;
        float4 v = *(const float4*)(in + (size_t)row * Cc + bx * 64 + cq * 4);
        tile[rt + i * 16][cq * 4 + 0] = v.x;
        tile[rt + i * 16][cq * 4 + 1] = v.y;
        tile[rt + i * 16][cq * 4 + 2] = v.z;
        tile[rt + i * 16][cq * 4 + 3] = v.w;
    }
    __syncthreads();
    const int cW = tid >> 3, rg = tid & 7;
    #pragma unroll
    for (int i = 0; i < 2; i++){
        int c = bx * 64 + cW + i * 32;
        float a0 = tile[rg * 4 + 0][cW + i * 32];
        float a1 = tile[rg * 4 + 1][cW + i * 32];
        float a2 = tile[rg * 4 + 2][cW + i * 32];
        float a3 = tile[rg * 4 + 3][cW + i * 32];
        uint2 pv;
        pv.x = pk2(a0, a1);
        pv.y = pk2(a2, a3);
        *(uint2*)(outp + (size_t)c * Rr + by * 32 + rg * 4) = pv;
    }
}

// ---------------- 128-tile deep-pipelined GEMM (QKV / W1) ----------------
// counted vmcnt(8), raw barriers, both-sides XOR swizzle, setprio.
// VFUSE (QKV only): V-column blocks write transposed into vt (A/B: -4.3 us).
template<bool BIAS, bool RELU, bool OBF16, bool AXISM, bool VFUSE>
__global__ __launch_bounds__(256, 2) void k_gemm128p(
    const u16* __restrict__ A, const u16* __restrict__ Bt,
    const float* __restrict__ bias,
    float* __restrict__ outF, u16* __restrict__ outH, u16* __restrict__ vtOut,
    int N, int Kfull, int NXT, int NMT, int NZ)
{
    __shared__ __align__(16) u16 lds[32768];  // 2 slots x (A 8K + B 8K) elems
    const int bid = blockIdx.x;
    const int xcd = bid & 7;
    const int r   = bid >> 3;
    int m_t, n_t, z;
    if constexpr (AXISM) {
        const int mper = NMT >> 3;
        n_t = r % NXT;
        int r2 = r / NXT;
        z = r2 % NZ;
        m_t = xcd * mper + r2 / NZ;
    } else {
        const int nper = NXT >> 3;
        n_t = xcd * nper + r % nper;
        int r2 = r / nper;
        m_t = r2 % NMT;
        z = r2 / NMT;
    }
    const int m0 = m_t * 128;
    const int n0 = n_t * 128;
    const int Kz = Kfull / NZ;
    const int kbeg = z * Kz;
    const int NT = Kz >> 6;

    const int tid  = threadIdx.x;
    const int w    = tid >> 6;
    const int lane = tid & 63;
    const int wr   = w >> 1, wc = w & 1;            // 2m x 2n wave grid
    const int lrow = lane & 15, lkg = lane >> 4;

    const int srow = tid >> 3;
    const int ssw  = ((tid & 7) ^ (srow & 7)) * 8;
    const u16* aSrc0 = A  + (size_t)(m0 +  0 + srow) * Kfull + kbeg + ssw;
    const u16* aSrc1 = A  + (size_t)(m0 + 32 + srow) * Kfull + kbeg + ssw;
    const u16* aSrc2 = A  + (size_t)(m0 + 64 + srow) * Kfull + kbeg + ssw;
    const u16* aSrc3 = A  + (size_t)(m0 + 96 + srow) * Kfull + kbeg + ssw;
    const u16* bSrc0 = Bt + (size_t)(n0 +  0 + srow) * Kfull + kbeg + ssw;
    const u16* bSrc1 = Bt + (size_t)(n0 + 32 + srow) * Kfull + kbeg + ssw;
    const u16* bSrc2 = Bt + (size_t)(n0 + 64 + srow) * Kfull + kbeg + ssw;
    const u16* bSrc3 = Bt + (size_t)(n0 + 96 + srow) * Kfull + kbeg + ssw;

    const int sw0 = ((0 + lkg) ^ (lrow & 7)) * 8;
    const int sw1 = ((4 + lkg) ^ (lrow & 7)) * 8;
    const int aBase = (wr * 64 + lrow) * 64;
    const int bBase = (wc * 64 + lrow) * 64 + 8192;

    f32x4 acc[4][4] = {};

    #define STAGE(s, st) do { \
        u16* ab_ = lds + (s) * 16384 + w * 512; \
        const int ko_ = (st) * 64; \
        gld16(aSrc0 + ko_, ab_);              \
        gld16(aSrc1 + ko_, ab_ + 2048);       \
        gld16(aSrc2 + ko_, ab_ + 4096);       \
        gld16(aSrc3 + ko_, ab_ + 6144);       \
        gld16(bSrc0 + ko_, ab_ + 8192);       \
        gld16(bSrc1 + ko_, ab_ + 10240);      \
        gld16(bSrc2 + ko_, ab_ + 12288);      \
        gld16(bSrc3 + ko_, ab_ + 14336);      \
    } while (0)

    STAGE(0, 0);
    STAGE(1, 1);
    asm volatile("s_waitcnt vmcnt(8)" ::: "memory");
    __builtin_amdgcn_s_barrier();
    __builtin_amdgcn_sched_barrier(0);

    for (int t = 0; t < NT; ++t){
        const int s = t & 1;
        const u16* As = lds + s * 16384;

        bf16x8 af0[4], bf0[4];
        #pragma unroll
        for (int i = 0; i < 4; i++) af0[i] = ldb8(As + aBase + i * 1024 + sw0);
        #pragma unroll
        for (int j = 0; j < 4; j++) bf0[j] = ldb8(As + bBase + j * 1024 + sw0);
        __builtin_amdgcn_s_setprio(1);
        #pragma unroll
        for (int i = 0; i < 4; i++)
            #pragma unroll
            for (int j = 0; j < 4; j++)
                acc[i][j] = mfma16(af0[i], bf0[j], acc[i][j]);
        __builtin_amdgcn_s_setprio(0);

        bf16x8 af1[4], bf1[4];
        #pragma unroll
        for (int i = 0; i < 4; i++) af1[i] = ldb8(As + aBase + i * 1024 + sw1);
        #pragma unroll
        for (int j = 0; j < 4; j++) bf1[j] = ldb8(As + bBase + j * 1024 + sw1);
        asm volatile("s_waitcnt lgkmcnt(0)" ::: "memory");
        __builtin_amdgcn_sched_barrier(0);
        __builtin_amdgcn_s_barrier();
        __builtin_amdgcn_sched_barrier(0);

        STAGE(s, (t + 2 < NT) ? t + 2 : NT - 1);

        __builtin_amdgcn_s_setprio(1);
        #pragma unroll
        for (int i = 0; i < 4; i++)
            #pragma unroll
            for (int j = 0; j < 4; j++)
                acc[i][j] = mfma16(af1[i], bf1[j], acc[i][j]);
        __builtin_amdgcn_s_setprio(0);

        asm volatile("s_waitcnt vmcnt(8)" ::: "memory");
        __builtin_amdgcn_s_barrier();
        __builtin_amdgcn_sched_barrier(0);
    }
    #undef STAGE

    float* outFz = outF;
    if (NZ > 1) outFz += (size_t)z * (NMT * 128) * N;

    #pragma unroll
    for (int i = 0; i < 4; i++){
        #pragma unroll
        for (int j = 0; j < 4; j++){
            const int c = n0 + 64 * wc + 16 * j + lrow;
            if (VFUSE && n0 >= 2048) {
                const int hv = (c - 2048) >> 6, dh = (c - 2048) & 63;
                const int r0 = m0 + 64 * wr + 16 * i + lkg * 4;
                const int bb = r0 >> 10, ss = r0 & 1023;
                uint2 pv;
                pv.x = pk2(acc[i][j][0], acc[i][j][1]);
                pv.y = pk2(acc[i][j][2], acc[i][j][3]);
                *(uint2*)(vtOut + (((size_t)((bb * 16 + hv) * 64 + dh)) << 10) + ss) = pv;
            } else {
                float bv = 0.0f;
                if constexpr (BIAS) bv = bias[c];
                #pragma unroll
                for (int e = 0; e < 4; e++){
                    const int rr = m0 + 64 * wr + 16 * i + lkg * 4 + e;
                    float vv = acc[i][j][e] + bv;
                    if constexpr (RELU) vv = fmaxf(vv, 0.0f);
                    const size_t idx = (size_t)rr * N + c;
                    if constexpr (OBF16) outH[idx] = f2bf(vv);
                    else                 outFz[idx] = vv;
                }
            }
        }
    }
}

// -------- 128x64-tile deep-pipelined GEMM (Wo / W2 split-K partials) --------
// Same validated ledger with 6 loads/stage -> vmcnt(6). LDS 48 KiB ->
// 2+ blocks/CU at grid 512 (vs 1 at grid 256 with the 128x128 tile) without
// the NZ4 partial-traffic penalty (+9.7 us measured).
__global__ __launch_bounds__(256, 2) void k_gemm64n(
    const u16* __restrict__ A, const u16* __restrict__ Bt,
    float* __restrict__ outF,
    int N, int Kfull, int NXT, int NMT, int NZ)
{
    __shared__ __align__(16) u16 lds[24576];  // 2 slots x (A 8K + B 4K) elems
    const int bid = blockIdx.x;
    const int xcd = bid & 7;
    const int r   = bid >> 3;
    const int mper = NMT >> 3;
    const int n_t = r % NXT;
    const int r2  = r / NXT;
    const int z   = r2 % NZ;
    const int m_t = xcd * mper + r2 / NZ;
    const int m0 = m_t * 128;
    const int n0 = n_t * 64;
    const int Kz = Kfull / NZ;
    const int kbeg = z * Kz;
    const int NT = Kz >> 6;

    const int tid  = threadIdx.x;
    const int w    = tid >> 6;
    const int lane = tid & 63;
    const int wr   = w >> 1, wc = w & 1;            // 2m x 2n wave grid
    const int lrow = lane & 15, lkg = lane >> 4;

    const int srow = tid >> 3;                       // 0..31
    const int ssw  = ((tid & 7) ^ (srow & 7)) * 8;
    const u16* aSrc0 = A  + (size_t)(m0 +  0 + srow) * Kfull + kbeg + ssw;
    const u16* aSrc1 = A  + (size_t)(m0 + 32 + srow) * Kfull + kbeg + ssw;
    const u16* aSrc2 = A  + (size_t)(m0 + 64 + srow) * Kfull + kbeg + ssw;
    const u16* aSrc3 = A  + (size_t)(m0 + 96 + srow) * Kfull + kbeg + ssw;
    const u16* bSrc0 = Bt + (size_t)(n0 +  0 + srow) * Kfull + kbeg + ssw;
    const u16* bSrc1 = Bt + (size_t)(n0 + 32 + srow) * Kfull + kbeg + ssw;

    const int sw0 = ((0 + lkg) ^ (lrow & 7)) * 8;
    const int sw1 = ((4 + lkg) ^ (lrow & 7)) * 8;
    const int aBase = (wr * 64 + lrow) * 64;
    const int bBase = (wc * 32 + lrow) * 64 + 8192;

    f32x4 acc[4][2] = {};

    #define STAGE6(s, st) do { \
        u16* ab_ = lds + (s) * 12288 + w * 512; \
        const int ko_ = (st) * 64; \
        gld16(aSrc0 + ko_, ab_);              \
        gld16(aSrc1 + ko_, ab_ + 2048);       \
        gld16(aSrc2 + ko_, ab_ + 4096);       \
        gld16(aSrc3 + ko_, ab_ + 6144);       \
        gld16(bSrc0 + ko_, ab_ + 8192);       \
        gld16(bSrc1 + ko_, ab_ + 10240);      \
    } while (0)

    STAGE6(0, 0);
    STAGE6(1, 1);
    asm volatile("s_waitcnt vmcnt(6)" ::: "memory");
    __builtin_amdgcn_s_barrier();
    __builtin_amdgcn_sched_barrier(0);

    for (int t = 0; t < NT; ++t){
        const int s = t & 1;
        const u16* As = lds + s * 12288;

        bf16x8 af0[4], bf0[2];
        #pragma unroll
        for (int i = 0; i < 4; i++) af0[i] = ldb8(As + aBase + i * 1024 + sw0);
        #pragma unroll
        for (int j = 0; j < 2; j++) bf0[j] = ldb8(As + bBase + j * 1024 + sw0);
        __builtin_amdgcn_s_setprio(1);
        #pragma unroll
        for (int i = 0; i < 4; i++)
            #pragma unroll
            for (int j = 0; j < 2; j++)
                acc[i][j] = mfma16(af0[i], bf0[j], acc[i][j]);
        __builtin_amdgcn_s_setprio(0);

        bf16x8 af1[4], bf1[2];
        #pragma unroll
        for (int i = 0; i < 4; i++) af1[i] = ldb8(As + aBase + i * 1024 + sw1);
        #pragma unroll
        for (int j = 0; j < 2; j++) bf1[j] = ldb8(As + bBase + j * 1024 + sw1);
        asm volatile("s_waitcnt lgkmcnt(0)" ::: "memory");
        __builtin_amdgcn_sched_barrier(0);
        __builtin_amdgcn_s_barrier();          // all waves done reading slot s
        __builtin_amdgcn_sched_barrier(0);

        STAGE6(s, (t + 2 < NT) ? t + 2 : NT - 1);

        __builtin_amdgcn_s_setprio(1);
        #pragma unroll
        for (int i = 0; i < 4; i++)
            #pragma unroll
            for (int j = 0; j < 2; j++)
                acc[i][j] = mfma16(af1[i], bf1[j], acc[i][j]);
        __builtin_amdgcn_s_setprio(0);

        asm volatile("s_waitcnt vmcnt(6)" ::: "memory");
        __builtin_amdgcn_s_barrier();          // slot s^1 (t+1) now ready
        __builtin_amdgcn_sched_barrier(0);
    }
    #undef STAGE6

    float* outFz = outF + (size_t)z * (NMT * 128) * N;
    #pragma unroll
    for (int i = 0; i < 4; i++){
        #pragma unroll
        for (int j = 0; j < 2; j++){
            const int c = n0 + 32 * wc + 16 * j + lrow;
            #pragma unroll
            for (int e = 0; e < 4; e++){
                const int rr = m0 + 64 * wr + 16 * i + lkg * 4 + e;
                outFz[(size_t)rr * N + c] = acc[i][j][e];
            }
        }
    }
}

// ---------------- head GEMM: 256x256 tile, 512 thr, BK=64, deep pipeline ----
__global__ __launch_bounds__(512, 2) void k_gemm_head256(
    const u16* __restrict__ A, const u16* __restrict__ Bt,
    float* __restrict__ out)
{
    __shared__ __align__(16) u16 lds[65536];
    const int bid = blockIdx.x;
    const int swz = (bid & 7) * 125 + (bid >> 3);   // XCD-chunked, 1000%8==0
    const int m0 = (swz >> 3) * 256;                // vocab tile
    const int n0 = (swz & 7) * 256;                 // token tile

    const int tid  = threadIdx.x;
    const int w    = tid >> 6;
    const int lane = tid & 63;
    const int wr   = w >> 2, wc = w & 3;            // 2m x 4n wave grid
    const int lrow = lane & 15, lkg = lane >> 4;

    const int srow = tid >> 3;
    const int ssw  = ((tid & 7) ^ (srow & 7)) * 8;
    const u16* aSrc0 = A  + (size_t)(m0 +   0 + srow) * D_MODEL + ssw;
    const u16* aSrc1 = A  + (size_t)(m0 +  64 + srow) * D_MODEL + ssw;
    const u16* aSrc2 = A  + (size_t)(m0 + 128 + srow) * D_MODEL + ssw;
    const u16* aSrc3 = A  + (size_t)(m0 + 192 + srow) * D_MODEL + ssw;
    const u16* bSrc0 = Bt + (size_t)(n0 +   0 + srow) * D_MODEL + ssw;
    const u16* bSrc1 = Bt + (size_t)(n0 +  64 + srow) * D_MODEL + ssw;
    const u16* bSrc2 = Bt + (size_t)(n0 + 128 + srow) * D_MODEL + ssw;
    const u16* bSrc3 = Bt + (size_t)(n0 + 192 + srow) * D_MODEL + ssw;

    const int sw0 = ((0 + lkg) ^ (lrow & 7)) * 8;
    const int sw1 = ((4 + lkg) ^ (lrow & 7)) * 8;
    const int aBase = (wr * 128 + lrow) * 64;
    const int bBase = (wc * 64  + lrow) * 64;

    f32x4 acc[8][4] = {};

    #define STAGE(s, st) do { \
        u16* ab_ = lds + (s) * 32768 + w * 512; \
        const int ko_ = (st) * 64; \
        gld16(aSrc0 + ko_, ab_);              \
        gld16(aSrc1 + ko_, ab_ + 4096);       \
        gld16(aSrc2 + ko_, ab_ + 8192);       \
        gld16(aSrc3 + ko_, ab_ + 12288);      \
        gld16(bSrc0 + ko_, ab_ + 16384);      \
        gld16(bSrc1 + ko_, ab_ + 20480);      \
        gld16(bSrc2 + ko_, ab_ + 24576);      \
        gld16(bSrc3 + ko_, ab_ + 28672);      \
    } while (0)

    STAGE(0, 0);
    STAGE(1, 1);
    asm volatile("s_waitcnt vmcnt(8)" ::: "memory");
    __builtin_amdgcn_s_barrier();
    __builtin_amdgcn_sched_barrier(0);

    const int NT = D_MODEL / 64;   // 16
    for (int t = 0; t < NT; ++t){
        const int s = t & 1;
        const u16* As = lds + s * 32768;
        const u16* Bs = As + 16384;

        bf16x8 af0[8], bf0[4];
        #pragma unroll
        for (int i = 0; i < 8; i++) af0[i] = ldb8(As + aBase + i * 1024 + sw0);
        #pragma unroll
        for (int j = 0; j < 4; j++) bf0[j] = ldb8(Bs + bBase + j * 1024 + sw0);
        __builtin_amdgcn_s_setprio(1);
        #pragma unroll
        for (int i = 0; i < 8; i++)
            #pragma unroll
            for (int j = 0; j < 4; j++)
                acc[i][j] = mfma16(af0[i], bf0[j], acc[i][j]);
        __builtin_amdgcn_s_setprio(0);

        bf16x8 af1[8], bf1[4];
        #pragma unroll
        for (int i = 0; i < 8; i++) af1[i] = ldb8(As + aBase + i * 1024 + sw1);
        #pragma unroll
        for (int j = 0; j < 4; j++) bf1[j] = ldb8(Bs + bBase + j * 1024 + sw1);
        asm volatile("s_waitcnt lgkmcnt(0)" ::: "memory");
        __builtin_amdgcn_sched_barrier(0);
        __builtin_amdgcn_s_barrier();
        __builtin_amdgcn_sched_barrier(0);

        STAGE(s, (t + 2 < NT) ? t + 2 : NT - 1);

        __builtin_amdgcn_s_setprio(1);
        #pragma unroll
        for (int i = 0; i < 8; i++)
            #pragma unroll
            for (int j = 0; j < 4; j++)
                acc[i][j] = mfma16(af1[i], bf1[j], acc[i][j]);
        __builtin_amdgcn_s_setprio(0);

        asm volatile("s_waitcnt vmcnt(8)" ::: "memory");
        __builtin_amdgcn_s_barrier();
        __builtin_amdgcn_sched_barrier(0);
    }
    #undef STAGE

    #pragma unroll
    for (int i = 0; i < 8; i++){
        const int m = m0 + wr * 128 + i * 16 + lkg * 4;
        #pragma unroll
        for (int j = 0; j < 4; j++){
            const int n = n0 + wc * 64 + j * 16 + lrow;
            float4 st;
            st.x = acc[i][j][0]; st.y = acc[i][j][1];
            st.z = acc[i][j][2]; st.w = acc[i][j][3];
            *(float4*)(out + (size_t)n * NVOCAB + m) = st;
        }
    }
}

// ---- flash attention: 1 wave / 16 q-rows, KVBLK=64, SWAPPED QK^T softmax ---
__global__ __launch_bounds__(256) void k_attn(const u16* __restrict__ qkv,
        const u16* __restrict__ vt, u16* __restrict__ ctx){
    const int wid  = (blockIdx.x << 2) + (threadIdx.x >> 6);
    const int lane = threadIdx.x & 63;
    const int qt = wid & 63;
    const int h  = (wid >> 6) & 15;
    const int b  = wid >> 10;
    const int q0 = qt * 16;
    const int lo = lane & 15, hi = lane >> 4;

    __shared__ __align__(16) u16 plds_all[4][16][72];
    u16 (*plds)[72] = plds_all[threadIdx.x >> 6];

    const u16* qbase = qkv + (size_t)(b * SEQ + q0 + lo) * QKV_LD + h * DKH + 8 * hi;
    const bf16x8 qf0 = ldb8(qbase);
    const bf16x8 qf1 = ldb8(qbase + 32);

    const int qrow = q0 + lo;
    float mr = -1e30f, lsum = 0.0f;
    f32x4 acc[4] = {};

    const int nkb = (q0 >> 6) + 1;
    const u16* kbase  = qkv + (size_t)(b * SEQ) * QKV_LD + 1024 + h * DKH;
    const u16* vtbase = vt + (size_t)((b * NHEADS + h) * DKH) * SEQ;

    for (int kb = 0; kb < nkb; ++kb){
        const int kc = kb * 64;
        f32x4 sg[4] = {};
        const u16* kp = kbase + (size_t)(kc + lo) * QKV_LD + 8 * hi;
        bf16x8 ka[4], kbv[4];
        #pragma unroll
        for (int g = 0; g < 4; g++){
            const u16* p = kp + (size_t)(16 * g) * QKV_LD;
            ka[g]  = ldb8(p);
            kbv[g] = ldb8(p + 32);
        }
        __builtin_amdgcn_s_setprio(1);
        #pragma unroll
        for (int g = 0; g < 4; g++){
            sg[g] = mfma16(ka[g],  qf0, sg[g]);   // SWAPPED: S[key][q]
            sg[g] = mfma16(kbv[g], qf1, sg[g]);
        }
        __builtin_amdgcn_s_setprio(0);

        float pm = -1e30f;
        #pragma unroll
        for (int g = 0; g < 4; g++){
            #pragma unroll
            for (int e = 0; e < 4; e++){
                const int key = kc + 16 * g + hi * 4 + e;
                float v = (key > qrow) ? -1e30f : sg[g][e] * 0.125f;
                sg[g][e] = v;
                pm = fmaxf(pm, v);
            }
        }
        pm = fmaxf(pm, __shfl_xor(pm, 16));
        pm = fmaxf(pm, __shfl_xor(pm, 32));
        const float mn = fmaxf(mr, pm);
        const float al = __expf(mr - mn);
        mr = mn;

        float rsum = 0.0f;
        u16* prow = plds[lo];
        #pragma unroll
        for (int g = 0; g < 4; g++){
            #pragma unroll
            for (int e = 0; e < 4; e++){
                float p = __expf(sg[g][e] - mn);
                rsum += p;
                prow[16 * g + hi * 4 + e] = f2bf(p);
            }
        }
        rsum += __shfl_xor(rsum, 16);
        rsum += __shfl_xor(rsum, 32);
        lsum = lsum * al + rsum;

        #pragma unroll
        for (int e = 0; e < 4; e++){
            const float ale = __shfl(al, hi * 4 + e);
            #pragma unroll
            for (int nt = 0; nt < 4; nt++) acc[nt][e] *= ale;
        }

        asm volatile("" ::: "memory");
        const bf16x8 pf0 = ldb8(&plds[lo][8 * hi]);
        const bf16x8 pf1 = ldb8(&plds[lo][32 + 8 * hi]);
        __builtin_amdgcn_s_setprio(1);
        #pragma unroll
        for (int nt = 0; nt < 4; nt++){
            const u16* vp = vtbase + (size_t)(16 * nt + lo) * SEQ + kc + 8 * hi;
            acc[nt] = mfma16(pf0, ldb8(vp),      acc[nt]);
            acc[nt] = mfma16(pf1, ldb8(vp + 32), acc[nt]);
        }
        __builtin_amdgcn_s_setprio(0);
    }
    #pragma unroll
    for (int e = 0; e < 4; e++){
        const float inv = 1.0f / __shfl(lsum, hi * 4 + e);
        const int r = q0 + hi * 4 + e;
        #pragma unroll
        for (int nt = 0; nt < 4; nt++){
            ctx[(size_t)(b * SEQ + r) * D_MODEL + h * DKH + 16 * nt + lo] =
                f2bf(acc[nt][e] * inv);
        }
    }
}

// ---------------- launcher ----------------
extern "C" void kernel_launch(void* const* d_in, const int* in_sizes, int n_in,
                              void* d_out, int out_size, void* d_ws, size_t ws_size,
                              hipStream_t stream){
    const int*   ids  = (const int*)  d_in[0];
    const float* tok  = (const float*)d_in[1];
    const float* pe   = (const float*)d_in[2];
    const float* Wq   = (const float*)d_in[3];
    const float* Wk   = (const float*)d_in[4];
    const float* Wv   = (const float*)d_in[5];
    const float* Wo   = (const float*)d_in[6];
    const float* bo   = (const float*)d_in[7];
    const float* W1   = (const float*)d_in[8];
    const float* b1   = (const float*)d_in[9];
    const float* W2   = (const float*)d_in[10];
    const float* b2   = (const float*)d_in[11];
    const float* ln1g = (const float*)d_in[12];
    const float* ln1b = (const float*)d_in[13];
    const float* ln2g = (const float*)d_in[14];
    const float* ln2b = (const float*)d_in[15];
    const float* lnfg = (const float*)d_in[16];
    const float* lnfb = (const float*)d_in[17];
    const float* Wh   = (const float*)d_in[18];
    float* out = (float*)d_out;

    char* ws = (char*)d_ws;
    size_t off = 0;
    auto alloc = [&](size_t bytes) -> void* {
        void* p = ws + off;
        off += (bytes + 255) & ~(size_t)255;
        return p;
    };
    float* x     = (float*)alloc((size_t)NTOK * D_MODEL * 4);   // 8 MB
    u16*   hbuf  = (u16*)  alloc((size_t)NTOK * D_MODEL * 2);   // 4 MB
    u16*   qkv   = (u16*)  alloc((size_t)NTOK * QKV_LD  * 2);   // 12 MB
    u16*   vt    = (u16*)  alloc((size_t)NTOK * D_MODEL * 2);   // 4 MB
    u16*   ctx   = (u16*)  alloc((size_t)NTOK * D_MODEL * 2);   // 4 MB
    u16*   f1    = (u16*)  alloc((size_t)NTOK * DFF     * 2);   // 16 MB
    float* pbuf  = (float*)alloc((size_t)2 * NTOK * D_MODEL * 4); // 16 MB
    u16*   wqkvT = (u16*)  alloc((size_t)QKV_LD * D_MODEL * 2); // 6 MB
    u16*   woT   = (u16*)  alloc((size_t)D_MODEL * D_MODEL * 2);// 2 MB
    u16*   w1T   = (u16*)  alloc((size_t)DFF * D_MODEL * 2);    // 8 MB
    u16*   w2T   = (u16*)  alloc((size_t)D_MODEL * DFF * 2);    // 8 MB
    u16*   whB   = (u16*)  alloc((size_t)NVOCAB * D_MODEL * 2); // 65.5 MB
    (void)ws_size; (void)in_sizes; (void)n_in; (void)out_size;

    k_embed<<<NTOK, 256, 0, stream>>>(ids, tok, pe, x);

    for (int l = 0; l < NLAYERS; l++){
        const size_t wdd = (size_t)l * D_MODEL * D_MODEL;
        const size_t wdf = (size_t)l * D_MODEL * DFF;
        const int tgrid = (l == 0) ? (6144 + 16000) : 6144;
        k_tconv_fused<<<tgrid, 256, 0, stream>>>(
            Wq + wdd, Wk + wdd, Wv + wdd, Wo + wdd, W1 + wdf, W2 + wdf,
            wqkvT, woT, w1T, w2T, Wh, whB);

        if (l == 0)
            k_ln<<<NTOK, 256, 0, stream>>>(x, ln1g, ln1b, hbuf);
        else
            k_ln_acc<2><<<NTOK, 256, 0, stream>>>(x, pbuf, b2 + (l - 1) * D_MODEL,
                ln1g + l * D_MODEL, ln1b + l * D_MODEL, hbuf);

        // QKV GEMM (+fused V-transpose): grid 384 = 8 xcd * 3 n * 16 m
        k_gemm128p<false, false, true, false, true><<<384, 256, 0, stream>>>(
            hbuf, wqkvT, nullptr, nullptr, qkv, vt, QKV_LD, D_MODEL, 24, 16, 1);
        k_attn<<<512, 256, 0, stream>>>(qkv, vt, ctx);

        // Wo GEMM split-K=2, BN=64 tile: grid 512 = 8 xcd * (16 n * 2 z * 2 m)
        k_gemm64n<<<512, 256, 0, stream>>>(
            ctx, woT, pbuf, D_MODEL, D_MODEL, 16, 16, 2);
        k_ln_acc<2><<<NTOK, 256, 0, stream>>>(x, pbuf, bo + l * D_MODEL,
            ln2g + l * D_MODEL, ln2b + l * D_MODEL, hbuf);

        // W1 GEMM: grid 512 = 8 xcd * 4 n * 16 m
        k_gemm128p<true, true, true, false, false><<<512, 256, 0, stream>>>(
            hbuf, w1T, b1 + l * DFF, nullptr, f1, nullptr, DFF, D_MODEL, 32, 16, 1);
        // W2 GEMM split-K=2, BN=64 tile: grid 512
        k_gemm64n<<<512, 256, 0, stream>>>(
            f1, w2T, pbuf, D_MODEL, DFF, 16, 16, 2);
    }

    k_ln_acc<2><<<NTOK, 256, 0, stream>>>(x, pbuf, b2 + 3 * D_MODEL,
        lnfg, lnfb, hbuf);
    // head GEMM: k_gemm_head256 — best measured (176-182 us, FETCH 115MB).
    k_gemm_head256<<<1000, 512, 0, stream>>>(whB, hbuf, out);
}